// Round 4
// baseline (478.480 us; speedup 1.0000x reference)
//
#include <hip/hip_runtime.h>
#include <math.h>

#define NATOM 32768
#define NMOL 8
#define PERM 4096
#define LOG2PERM 12
#define NPAIR 2097152
#define NKK 625           // 25x25 k-grid, invalid entries get coef=0
#define CAPM 32768        // per-molecule record capacity (~26k expected)

#define KE_C 14.3996f
#define ALPHA_C 0.3f
#define CUTOFF_C 6.0f
#define SQRT_ALPHA_C 0.5477225575051661f   // sqrt(0.3)
#define ACONST_C 0.6180387232371366f       // 2*sqrt(alpha/pi)
#define SELF_C 0.3090193616185683f         // sqrt(alpha/pi)
#define TWO_PI_C 6.283185307179586f
#define LN_CUTOFF_C 1.791759469228055f     // ln(6)

// persistent device state
__device__ float4 g_X[NATOM];            // x,y,z,q
__device__ float4 g_G[NATOM];            // dE/dX
__device__ float4 g_HV[NATOM];           // H*V
__device__ float  g_qf[NATOM];           // q*film
__device__ unsigned char g_filmb[NATOM];
__device__ float4 g_kvc[NMOL*NKK];       // kvx,kvy,kvz,coef
__device__ float2 g_S[NMOL*NKK];         // S_re,S_im (all atoms)
__device__ float2 g_Sf[NMOL*NKK];        // S_re,S_im (film atoms, q*film weights)
__device__ float4 g_recA[NMOL*CAPM];     // packed ij+film, rx, ry, rz
__device__ float4 g_recB[NMOL*CAPM];     // r0, n, qq, d2
__device__ unsigned g_cnt[NMOL];
__device__ float g_recipM[NMOL][9];
__device__ float g_vbox[NMOL];
__device__ float g_self[NMOL];
__device__ float g_qfilm[NMOL];
__device__ float g_yreal[NMOL];
__device__ float g_yborn[NMOL];
__device__ float g_yrecip[NMOL];
__device__ float g_Fm[NMOL][3];
__device__ float g_norm2[NMOL];
__device__ float g_D, g_Dd, g_C2, g_FRC;

__device__ __forceinline__ float waveReduce(float v){
#pragma unroll
    for (int off = 32; off > 0; off >>= 1) v += __shfl_down(v, off, 64);
    return v;
}

__global__ void k_zero(){
    int id = threadIdx.x;
    if (id < NMOL){ g_cnt[id] = 0u; g_self[id] = 0.f; g_qfilm[id] = 0.f; }
    if (id == 0){ g_D = 0.f; g_Dd = 0.f; }
}

__global__ void k_prep(const float* cell){
    int m = threadIdx.x;
    if (m < NMOL){
        const float* c = cell + 9*m;
        float a=c[0],b=c[1],cc=c[2],d=c[3],e=c[4],f=c[5],g=c[6],h=c[7],i=c[8];
        float det = a*(e*i - f*h) - b*(d*i - f*g) + cc*(d*h - e*g);
        float inv = 1.f/det;
        float i00=(e*i-f*h)*inv,  i01=(cc*h-b*i)*inv, i02=(b*f-cc*e)*inv;
        float i10=(f*g-d*i)*inv,  i11=(a*i-cc*g)*inv, i12=(cc*d-a*f)*inv;
        float i20=(d*h-e*g)*inv,  i21=(b*g-a*h)*inv,  i22=(a*e-b*d)*inv;
        g_recipM[m][0]=TWO_PI_C*i00; g_recipM[m][1]=TWO_PI_C*i10; g_recipM[m][2]=TWO_PI_C*i20;
        g_recipM[m][3]=TWO_PI_C*i01; g_recipM[m][4]=TWO_PI_C*i11; g_recipM[m][5]=TWO_PI_C*i21;
        g_recipM[m][6]=TWO_PI_C*i02; g_recipM[m][7]=TWO_PI_C*i12; g_recipM[m][8]=TWO_PI_C*i22;
        g_vbox[m] = fabsf(det);
    }
    __syncthreads();
    if (threadIdx.x == 0){
        float c2 = 0.f;
        for (int mm = 0; mm < NMOL; ++mm) c2 += TWO_PI_C/g_vbox[mm];
        g_C2 = c2;
        g_FRC = (float)(erfc(sqrt(0.3)*6.0)/6.0);
    }
}

__global__ void k_kvec(){
    int id = blockIdx.x*blockDim.x + threadIdx.x;
    if (id >= NMOL*NKK) return;
    int m = id / NKK;
    int kk = id % NKK;
    int ix = kk / 25, iy = kk % 25;
    float kx = (ix <= 12) ? (float)ix : (float)(-(ix-12));
    float ky = (iy <= 12) ? (float)iy : (float)(-(iy-12));
    float nrm = kx*kx + ky*ky;
    float kvx = kx*g_recipM[m][0] + ky*g_recipM[m][3];
    float kvy = kx*g_recipM[m][1] + ky*g_recipM[m][4];
    float kvz = kx*g_recipM[m][2] + ky*g_recipM[m][5];
    float coef = 0.f;
    if (nrm != 0.f && nrm <= 146.f){
        float ksq = kvx*kvx + kvy*kvy + kvz*kvz;
        coef = (TWO_PI_C/g_vbox[m]) * expf(-0.25f*ksq/ALPHA_C) / ksq;
    }
    g_kvc[id] = make_float4(kvx, kvy, kvz, coef);
}

__global__ void k_shift(const float* q, const float* R, const float* shift, const int* is_film){
    int n = blockIdx.x*blockDim.x + threadIdx.x;
    int m = n >> LOG2PERM;
    int film = is_film[n];
    float qn = q[n];
    float x = R[3*n+0], y = R[3*n+1], z = R[3*n+2];
    if (film){ x += shift[3*m+0]; y += shift[3*m+1]; z += shift[3*m+2]; }
    g_X[n] = make_float4(x, y, z, qn);
    g_filmb[n] = (unsigned char)film;
    float qf = film ? qn : 0.f;
    g_qf[n] = qf;
    float vD = waveReduce(qn*z);
    float vS = waveReduce(qn*qn);
    float vQ = waveReduce(qf);
    __shared__ float red[12];
    int lane = threadIdx.x & 63, w = threadIdx.x >> 6;
    if (!lane){ red[w] = vD; red[4+w] = vS; red[8+w] = vQ; }
    __syncthreads();
    if (threadIdx.x == 0){
        atomicAdd(&g_D, red[0]+red[1]+red[2]+red[3]);
        atomicAdd(&g_self[m], red[4]+red[5]+red[6]+red[7]);
        atomicAdd(&g_qfilm[m], red[8]+red[9]+red[10]+red[11]);
    }
}

// single-pass filter: compact surviving pairs into per-molecule buckets.
// record: local indices + film bits packed in one u32; displacement; params.
#define FB 256
#define FBATCH 4
#define FPB (FB*2*FBATCH)   // 2048 pairs per block
__global__ void k_filter(const int* idx_i, const int* idx_j, const float* offsets,
                         const float* r0_ij, const float* n_ij){
    __shared__ unsigned s_cnt[NMOL], s_base[NMOL];
    int tid = threadIdx.x;
    int p0 = blockIdx.x*FPB;
    for (int b = 0; b < FBATCH; ++b){
        int pA = p0 + b*(FB*2) + tid;
        int pB = pA + FB;
        int iA = idx_i[pA], jA = idx_j[pA];
        int iB = idx_i[pB], jB = idx_j[pB];
        float4 xiA = g_X[iA], xjA = g_X[jA];
        float4 xiB = g_X[iB], xjB = g_X[jB];
        float rxA = xjA.x - xiA.x + offsets[3*pA+0];
        float ryA = xjA.y - xiA.y + offsets[3*pA+1];
        float rzA = xjA.z - xiA.z + offsets[3*pA+2];
        float rxB = xjB.x - xiB.x + offsets[3*pB+0];
        float ryB = xjB.y - xiB.y + offsets[3*pB+1];
        float rzB = xjB.z - xiB.z + offsets[3*pB+2];
        float d2A = rxA*rxA + ryA*ryA + rzA*rzA;
        float d2B = rxB*rxB + ryB*ryB + rzB*rzB;
        bool sA = d2A < CUTOFF_C*CUTOFF_C;
        bool sB = d2B < CUTOFF_C*CUTOFF_C;
        int mA = iA >> LOG2PERM, mB = iB >> LOG2PERM;
        if (tid < NMOL) s_cnt[tid] = 0u;
        __syncthreads();
        unsigned rA = 0u, rB = 0u;
        if (sA) rA = atomicAdd(&s_cnt[mA], 1u);
        if (sB) rB = atomicAdd(&s_cnt[mB], 1u);
        __syncthreads();
        if (tid < NMOL){
            unsigned c = s_cnt[tid];
            s_base[tid] = c ? atomicAdd(&g_cnt[tid], c) : 0u;
        }
        __syncthreads();
        if (sA){
            unsigned slot = s_base[mA] + rA;
            if (slot < CAPM){
                unsigned fi = g_filmb[iA], fj = g_filmb[jA];
                unsigned pk = (unsigned)(iA & 4095) | ((unsigned)(jA & 4095) << 12) | (fi << 24) | (fj << 25);
                int o = mA*CAPM + (int)slot;
                g_recA[o] = make_float4(__uint_as_float(pk), rxA, ryA, rzA);
                g_recB[o] = make_float4(r0_ij[pA], n_ij[pA], xiA.w*xjA.w, d2A);
            }
        }
        if (sB){
            unsigned slot = s_base[mB] + rB;
            if (slot < CAPM){
                unsigned fi = g_filmb[iB], fj = g_filmb[jB];
                unsigned pk = (unsigned)(iB & 4095) | ((unsigned)(jB & 4095) << 12) | (fi << 24) | (fj << 25);
                int o = mB*CAPM + (int)slot;
                g_recA[o] = make_float4(__uint_as_float(pk), rxB, ryB, rzB);
                g_recB[o] = make_float4(r0_ij[pB], n_ij[pB], xiB.w*xjB.w, d2B);
            }
        }
    }
}

// one pass computes S (all atoms) and S_film (q*film weights)
__global__ void k_sfac(){
    int bid = blockIdx.x;
    int m = bid / NKK;
    float4 kvc = g_kvc[bid];
    if (kvc.w == 0.f) return;
    float sre = 0.f, sim = 0.f, fre = 0.f, fim = 0.f;
    for (int a = threadIdx.x; a < PERM; a += blockDim.x){
        int n = (m << LOG2PERM) + a;
        float4 x = g_X[n];
        float qf = g_qf[n];
        float th = kvc.x*x.x + kvc.y*x.y + kvc.z*x.z;
        float s, c;
        __sincosf(th, &s, &c);
        sre += x.w*c; sim += x.w*s;
        fre += qf*c;  fim += qf*s;
    }
    sre = waveReduce(sre); sim = waveReduce(sim);
    fre = waveReduce(fre); fim = waveReduce(fim);
    __shared__ float red[16];
    int lane = threadIdx.x & 63, w = threadIdx.x >> 6;
    if (!lane){ red[w] = sre; red[4+w] = sim; red[8+w] = fre; red[12+w] = fim; }
    __syncthreads();
    if (threadIdx.x == 0){
        g_S[bid]  = make_float2(red[0]+red[1]+red[2]+red[3],   red[4]+red[5]+red[6]+red[7]);
        g_Sf[bid] = make_float2(red[8]+red[9]+red[10]+red[11], red[12]+red[13]+red[14]+red[15]);
    }
}

__global__ void k_recip_energy(){
    int m = blockIdx.x;
    float acc = 0.f;
    for (int kk = threadIdx.x; kk < NKK; kk += blockDim.x){
        float4 kvc = g_kvc[m*NKK + kk];
        float2 S = g_S[m*NKK + kk];
        acc += kvc.w*(S.x*S.x + S.y*S.y);
    }
    acc = waveReduce(acc);
    __shared__ float red[4];
    int lane = threadIdx.x & 63, w = threadIdx.x >> 6;
    if (!lane) red[w] = acc;
    __syncthreads();
    if (threadIdx.x == 0){
        float yew = red[0]+red[1]+red[2]+red[3];
        float D = g_D;
        float yslab = KE_C*(TWO_PI_C/g_vbox[m])*D*D;
        g_yrecip[m] = KE_C*(yew - SELF_C*g_self[m]) + yslab;
    }
}

// one block per molecule; force accumulation in LDS (4096 atoms x 3), plain store.
template<int PASS>
__launch_bounds__(1024, 1)
__global__ void k_pairs_lds(){
    __shared__ float s_acc[PERM*3];    // 48 KB
    __shared__ float redE[32];
    int m = blockIdx.x;
    int tid = threadIdx.x;
    for (int a = tid; a < PERM*3; a += 1024) s_acc[a] = 0.f;
    float Fx = 0.f, Fy = 0.f, Fz = 0.f;
    if (PASS){ Fx = g_Fm[m][0]; Fy = g_Fm[m][1]; Fz = g_Fm[m][2]; }
    float FRC = g_FRC;
    __syncthreads();
    int nrec = (int)g_cnt[m]; if (nrec > CAPM) nrec = CAPM;
    float er_sum = 0.f, eb_sum = 0.f;
    for (int r = tid; r < nrec; r += 1024){
        float4 A = g_recA[m*CAPM + r];
        float4 B = g_recB[m*CAPM + r];
        unsigned pk = __float_as_uint(A.x);
        int il = pk & 4095, jl = (pk >> 12) & 4095;
        float rx = A.y, ry = A.z, rz = A.w;
        float r0 = B.x, nij = B.y, qq = B.z, d2 = B.w;
        float d = sqrtf(d2);
        float inv_d = 1.f/d;
        float Bc = fabsf(qq)*__expf((nij - 1.f)*__logf(r0))/nij;
        float er = erfcf(SQRT_ALPHA_C*d);
        float expt = __expf(-ALPHA_C*d2);
        float dmn = __expf(-nij*__logf(d));               // d^-n
        float fp = -ACONST_C*expt*inv_d - er*inv_d*inv_d; // f'(d)
        float Up = 0.5f*KE_C*(qq*fp - Bc*nij*dmn*inv_d);  // U'(d)
        if (PASS == 0){
            er_sum += qq*(er*inv_d - FRC);
            eb_sum += Bc*(dmn - __expf(-nij*LN_CUTOFF_C));
            float sc = Up*inv_d;
            float gx = sc*rx, gy = sc*ry, gz = sc*rz;
            atomicAdd(&s_acc[jl*3+0],  gx); atomicAdd(&s_acc[jl*3+1],  gy); atomicAdd(&s_acc[jl*3+2],  gz);
            atomicAdd(&s_acc[il*3+0], -gx); atomicAdd(&s_acc[il*3+1], -gy); atomicAdd(&s_acc[il*3+2], -gz);
        } else {
            float fpp = ACONST_C*expt*(2.f*ALPHA_C + 2.f*inv_d*inv_d) + 2.f*er*inv_d*inv_d*inv_d;
            float Upp = 0.5f*KE_C*(qq*fpp + Bc*nij*(nij+1.f)*dmn*inv_d*inv_d);
            float dsg = (float)((pk >> 25) & 1) - (float)((pk >> 24) & 1);  // fj - fi
            float dvx = dsg*Fx, dvy = dsg*Fy, dvz = dsg*Fz;
            float ddot = (rx*dvx + ry*dvy + rz*dvz)*inv_d;
            float ui = Up*inv_d;
            float c1 = (Upp - ui)*ddot*inv_d;
            float gx = c1*rx + ui*dvx;
            float gy = c1*ry + ui*dvy;
            float gz = c1*rz + ui*dvz;
            atomicAdd(&s_acc[jl*3+0],  gx); atomicAdd(&s_acc[jl*3+1],  gy); atomicAdd(&s_acc[jl*3+2],  gz);
            atomicAdd(&s_acc[il*3+0], -gx); atomicAdd(&s_acc[il*3+1], -gy); atomicAdd(&s_acc[il*3+2], -gz);
        }
    }
    if (PASS == 0){
        er_sum = waveReduce(er_sum); eb_sum = waveReduce(eb_sum);
        int lane = tid & 63, w = tid >> 6;
        if (!lane){ redE[w] = er_sum; redE[16+w] = eb_sum; }
    }
    __syncthreads();
    if (PASS == 0 && tid == 0){
        float a = 0.f, b = 0.f;
        for (int k2 = 0; k2 < 16; ++k2){ a += redE[k2]; b += redE[16+k2]; }
        g_yreal[m] = a; g_yborn[m] = b;
    }
    int base = m << LOG2PERM;
    float4* T = PASS ? g_HV : g_G;
    for (int a = tid; a < PERM; a += 1024){
        T[base+a] = make_float4(s_acc[a*3+0], s_acc[a*3+1], s_acc[a*3+2], 0.f);
    }
}

// reciprocal gradient via phasor recurrence; PASS1 builds Sdot analytically:
// Sd = (k.Fm) * i * S_film  => Sd_re=-(k.Fm)Sf_im, Sd_im=(k.Fm)Sf_re
#define RG_BLOCK 128
template<int PASS>
__global__ void k_recip_grad(){
    __shared__ float2 s_u[NKK];
    __shared__ float2 s_v[NKK];
    __shared__ float  s_b[6];
    int tid = threadIdx.x;
    int n = blockIdx.x*RG_BLOCK + tid;
    int m = n >> LOG2PERM;
    if (tid < 6) s_b[tid] = g_recipM[m][tid];
    float Fx = 0.f, Fy = 0.f, Fz = 0.f;
    if (PASS){ Fx = g_Fm[m][0]; Fy = g_Fm[m][1]; Fz = g_Fm[m][2]; }
    for (int a = tid; a < NKK; a += RG_BLOCK){
        int kx = a/25 - 12, ky = a%25 - 12;
        int ixo = (kx >= 0) ? kx : 12 - kx;
        int iyo = (ky >= 0) ? ky : 12 - ky;
        int src = m*NKK + ixo*25 + iyo;
        float4 kv = g_kvc[src];
        float c = kv.w;
        float2 S = g_S[src];
        s_u[a] = make_float2(c*S.x, c*S.y);
        if (PASS){
            float2 Sf = g_Sf[src];
            float kvF = kv.x*Fx + kv.y*Fy + kv.z*Fz;
            s_v[a] = make_float2(-c*kvF*Sf.y, c*kvF*Sf.x);
        }
    }
    __syncthreads();
    float4 x4 = g_X[n];
    float b1x=s_b[0], b1y=s_b[1], b1z=s_b[2];
    float b2x=s_b[3], b2y=s_b[4], b2z=s_b[5];
    float th1 = b1x*x4.x + b1y*x4.y + b1z*x4.z;
    float th2 = b2x*x4.x + b2y*x4.y + b2z*x4.z;
    float E1s, E1c, E2s, E2c, Ps, Pc, Q0s, Q0c;
    sincosf(th1, &E1s, &E1c);
    sincosf(th2, &E2s, &E2c);
    sincosf(-12.f*th1, &Ps, &Pc);
    sincosf(-12.f*th2, &Q0s, &Q0c);
    float phi1 = 0.f, phi2 = 0.f;
    if (PASS){
        float film = (float)g_filmb[n];
        phi1 = film*(b1x*Fx + b1y*Fy + b1z*Fz);
        phi2 = film*(b2x*Fx + b2y*Fy + b2z*Fz);
    }
    float A1 = 0.f, A2 = 0.f;
    int a = 0;
    for (int kxi = 0; kxi < 25; ++kxi){
        float kx = (float)(kxi - 12);
        float pc = Pc*Q0c - Ps*Q0s;
        float ps = Pc*Q0s + Ps*Q0c;
        for (int kyi = 0; kyi < 25; ++kyi, ++a){
            float ky = (float)(kyi - 12);
            float2 u = s_u[a];
            float t;
            if (PASS == 0){
                t = u.y*pc - u.x*ps;
            } else {
                float2 v = s_v[a];
                float thd = kx*phi1 + ky*phi2;
                t = v.y*pc - v.x*ps - (u.y*ps + u.x*pc)*thd;
            }
            A1 += t*kx; A2 += t*ky;
            float npc = pc*E2c - ps*E2s;
            float nps = pc*E2s + ps*E2c;
            pc = npc; ps = nps;
        }
        float nPc = Pc*E1c - Ps*E1s;
        float nPs = Pc*E1s + Ps*E1c;
        Pc = nPc; Ps = nPs;
    }
    float gx = A1*b1x + A2*b2x;
    float gy = A1*b1y + A2*b2y;
    float gz = A1*b1z + A2*b2z;
    float sc = 2.f*KE_C*x4.w;
    float slab = 2.f*KE_C*g_C2*x4.w*(PASS ? g_Dd : g_D);
    float4* T = PASS ? g_HV : g_G;
    float4 t0 = T[n];
    t0.x += sc*gx;
    t0.y += sc*gy;
    t0.z += sc*gz + slab;
    T[n] = t0;
}

__global__ void k_reduce_F(){
    int m = blockIdx.x;
    float fx = 0.f, fy = 0.f, fz = 0.f;
    for (int a = threadIdx.x; a < PERM; a += blockDim.x){
        int n = (m << LOG2PERM) + a;
        float film = (float)g_filmb[n];
        float4 g = g_G[n];
        fx -= film*g.x; fy -= film*g.y; fz -= film*g.z;
    }
    fx = waveReduce(fx); fy = waveReduce(fy); fz = waveReduce(fz);
    __shared__ float red[12];
    int lane = threadIdx.x & 63, w = threadIdx.x >> 6;
    if (!lane){ red[w] = fx; red[4+w] = fy; red[8+w] = fz; }
    __syncthreads();
    if (threadIdx.x == 0){
        float FX = red[0]+red[1]+red[2]+red[3];
        float FY = red[4]+red[5]+red[6]+red[7];
        float FZ = red[8]+red[9]+red[10]+red[11];
        g_Fm[m][0] = FX; g_Fm[m][1] = FY; g_Fm[m][2] = FZ;
        g_norm2[m] = FX*FX + FY*FY + FZ*FZ;
        atomicAdd(&g_Dd, FZ*g_qfilm[m]);   // Dd = sum_m Fz * sum(q*film)
    }
}

__global__ void k_final(float* out){
    int m = blockIdx.x;
    float ax = 0.f, ay = 0.f, az = 0.f;
    for (int a = threadIdx.x; a < PERM; a += blockDim.x){
        int n = (m << LOG2PERM) + a;
        float film = (float)g_filmb[n];
        float4 hv = g_HV[n];
        ax += film*hv.x; ay += film*hv.y; az += film*hv.z;
    }
    ax = waveReduce(ax); ay = waveReduce(ay); az = waveReduce(az);
    __shared__ float red[12];
    int lane = threadIdx.x & 63, w = threadIdx.x >> 6;
    if (!lane){ red[w] = ax; red[4+w] = ay; red[8+w] = az; }
    __syncthreads();
    if (threadIdx.x == 0){
        float AX = red[0]+red[1]+red[2]+red[3];
        float AY = red[4]+red[5]+red[6]+red[7];
        float AZ = red[8]+red[9]+red[10]+red[11];
        out[32 + 3*m + 0] = -2.f*AX;
        out[32 + 3*m + 1] = -2.f*AY;
        out[32 + 3*m + 2] = -2.f*AZ;
        float yr = 0.5f*KE_C*g_yreal[m];
        float yb = 0.5f*KE_C*g_yborn[m];
        float yc = yr + g_yrecip[m];
        out[0  + m] = yc + yb;
        out[8  + m] = yc;
        out[16 + m] = yb;
        out[24 + m] = g_norm2[m];
    }
}

extern "C" void kernel_launch(void* const* d_in, const int* in_sizes, int n_in,
                              void* d_out, int out_size, void* d_ws, size_t ws_size,
                              hipStream_t stream){
    const float* q       = (const float*)d_in[0];
    const float* R       = (const float*)d_in[1];
    const float* shift   = (const float*)d_in[2];
    const float* cell    = (const float*)d_in[3];
    const float* offsets = (const float*)d_in[4];
    const float* r0_ij   = (const float*)d_in[5];
    const float* n_ij    = (const float*)d_in[6];
    const int*   idx_i   = (const int*)d_in[7];
    const int*   idx_j   = (const int*)d_in[8];
    const int*   is_film = (const int*)d_in[10];
    float* out = (float*)d_out;

    k_zero<<<dim3(1), dim3(64), 0, stream>>>();
    k_prep<<<dim3(1), dim3(64), 0, stream>>>(cell);
    k_kvec<<<dim3((NMOL*NKK + 255)/256), dim3(256), 0, stream>>>();
    k_shift<<<dim3(NATOM/256), dim3(256), 0, stream>>>(q, R, shift, is_film);
    k_filter<<<dim3(NPAIR/FPB), dim3(FB), 0, stream>>>(idx_i, idx_j, offsets, r0_ij, n_ij);
    k_sfac<<<dim3(NMOL*NKK), dim3(256), 0, stream>>>();
    k_recip_energy<<<dim3(NMOL), dim3(256), 0, stream>>>();
    k_pairs_lds<0><<<dim3(NMOL), dim3(1024), 0, stream>>>();
    k_recip_grad<0><<<dim3(NATOM/RG_BLOCK), dim3(RG_BLOCK), 0, stream>>>();
    k_reduce_F<<<dim3(NMOL), dim3(256), 0, stream>>>();
    k_pairs_lds<1><<<dim3(NMOL), dim3(1024), 0, stream>>>();
    k_recip_grad<1><<<dim3(NATOM/RG_BLOCK), dim3(RG_BLOCK), 0, stream>>>();
    k_final<<<dim3(NMOL), dim3(256), 0, stream>>>(out);
}

// Round 5
// 166.403 us; speedup vs baseline: 2.8754x; 2.8754x over previous
//
#include <hip/hip_runtime.h>
#include <math.h>

#define NATOM 32768
#define NMOL 8
#define PERM 4096
#define LOG2PERM 12
#define NPAIR 2097152
#define NKK 625           // 25x25 k-grid, invalid entries get coef=0
#define CAPM 32768        // per-molecule record capacity (~24k expected)
#define BPM 32            // partial-accumulator blocks per molecule

#define KE_C 14.3996f
#define ALPHA_C 0.3f
#define CUTOFF_C 6.0f
#define SQRT_ALPHA_C 0.5477225575051661f   // sqrt(0.3)
#define ACONST_C 0.6180387232371366f       // 2*sqrt(alpha/pi)
#define SELF_C 0.3090193616185683f         // sqrt(alpha/pi)
#define TWO_PI_C 6.283185307179586f
#define LN_CUTOFF_C 1.791759469228055f     // ln(6)

// persistent device state
__device__ float4 g_X[NATOM];            // x,y,z,q
__device__ float  g_Gf[NATOM*3];         // dE/dX (pair part written by greduce, recip added)
__device__ float  g_HVf[NATOM*3];        // H*V
__device__ float  g_part[(size_t)NMOL*BPM*PERM*3];  // per-block force partials
__device__ float  g_qf[NATOM];           // q*film
__device__ unsigned char g_filmb[NATOM];
__device__ float4 g_kvc[NMOL*NKK];       // kvx,kvy,kvz,coef
__device__ float2 g_S[NMOL*NKK];         // S_re,S_im (all atoms)
__device__ float2 g_Sf[NMOL*NKK];        // S_re,S_im (film atoms, q*film weights)
__device__ float4 g_recA[NMOL*CAPM];     // packed ij+film, rx, ry, rz
__device__ float4 g_recB[NMOL*CAPM];     // r0, n, qq, d2
__device__ unsigned g_cnt[NMOL];
__device__ float g_recipM[NMOL][9];
__device__ float g_vbox[NMOL];
__device__ float g_self[NMOL];
__device__ float g_qfilm[NMOL];
__device__ float g_yreal[NMOL];
__device__ float g_yborn[NMOL];
__device__ float g_Fm[NMOL][3];
__device__ float g_norm2[NMOL];
__device__ float g_D, g_Dd, g_C2, g_FRC;

__device__ __forceinline__ float waveReduce(float v){
#pragma unroll
    for (int off = 32; off > 0; off >>= 1) v += __shfl_down(v, off, 64);
    return v;
}

// zero + per-molecule cell prep (1 block)
__global__ void k_prep(const float* cell){
    int m = threadIdx.x;
    if (m < NMOL){
        g_cnt[m] = 0u; g_self[m] = 0.f; g_qfilm[m] = 0.f;
        g_yreal[m] = 0.f; g_yborn[m] = 0.f;
    }
    if (m == 0){ g_D = 0.f; g_Dd = 0.f; }
    if (m < NMOL){
        const float* c = cell + 9*m;
        float a=c[0],b=c[1],cc=c[2],d=c[3],e=c[4],f=c[5],g=c[6],h=c[7],i=c[8];
        float det = a*(e*i - f*h) - b*(d*i - f*g) + cc*(d*h - e*g);
        float inv = 1.f/det;
        float i00=(e*i-f*h)*inv,  i01=(cc*h-b*i)*inv, i02=(b*f-cc*e)*inv;
        float i10=(f*g-d*i)*inv,  i11=(a*i-cc*g)*inv, i12=(cc*d-a*f)*inv;
        float i20=(d*h-e*g)*inv,  i21=(b*g-a*h)*inv,  i22=(a*e-b*d)*inv;
        g_recipM[m][0]=TWO_PI_C*i00; g_recipM[m][1]=TWO_PI_C*i10; g_recipM[m][2]=TWO_PI_C*i20;
        g_recipM[m][3]=TWO_PI_C*i01; g_recipM[m][4]=TWO_PI_C*i11; g_recipM[m][5]=TWO_PI_C*i21;
        g_recipM[m][6]=TWO_PI_C*i02; g_recipM[m][7]=TWO_PI_C*i12; g_recipM[m][8]=TWO_PI_C*i22;
        g_vbox[m] = fabsf(det);
    }
    __syncthreads();
    if (threadIdx.x == 0){
        float c2 = 0.f;
        for (int mm = 0; mm < NMOL; ++mm) c2 += TWO_PI_C/g_vbox[mm];
        g_C2 = c2;
        g_FRC = (float)(erfc(sqrt(0.3)*6.0)/6.0);
    }
}

__global__ void k_kvec(){
    int id = blockIdx.x*blockDim.x + threadIdx.x;
    if (id >= NMOL*NKK) return;
    int m = id / NKK;
    int kk = id % NKK;
    int ix = kk / 25, iy = kk % 25;
    float kx = (ix <= 12) ? (float)ix : (float)(-(ix-12));
    float ky = (iy <= 12) ? (float)iy : (float)(-(iy-12));
    float nrm = kx*kx + ky*ky;
    float kvx = kx*g_recipM[m][0] + ky*g_recipM[m][3];
    float kvy = kx*g_recipM[m][1] + ky*g_recipM[m][4];
    float kvz = kx*g_recipM[m][2] + ky*g_recipM[m][5];
    float coef = 0.f;
    if (nrm != 0.f && nrm <= 146.f){
        float ksq = kvx*kvx + kvy*kvy + kvz*kvz;
        coef = (TWO_PI_C/g_vbox[m]) * expf(-0.25f*ksq/ALPHA_C) / ksq;
    }
    g_kvc[id] = make_float4(kvx, kvy, kvz, coef);
}

__global__ void k_shift(const float* q, const float* R, const float* shift, const int* is_film){
    int n = blockIdx.x*blockDim.x + threadIdx.x;
    int m = n >> LOG2PERM;
    int film = is_film[n];
    float qn = q[n];
    float x = R[3*n+0], y = R[3*n+1], z = R[3*n+2];
    if (film){ x += shift[3*m+0]; y += shift[3*m+1]; z += shift[3*m+2]; }
    g_X[n] = make_float4(x, y, z, qn);
    g_filmb[n] = (unsigned char)film;
    float qf = film ? qn : 0.f;
    g_qf[n] = qf;
    float vD = waveReduce(qn*z);
    float vS = waveReduce(qn*qn);
    float vQ = waveReduce(qf);
    __shared__ float red[12];
    int lane = threadIdx.x & 63, w = threadIdx.x >> 6;
    if (!lane){ red[w] = vD; red[4+w] = vS; red[8+w] = vQ; }
    __syncthreads();
    if (threadIdx.x == 0){
        atomicAdd(&g_D, red[0]+red[1]+red[2]+red[3]);
        atomicAdd(&g_self[m], red[4]+red[5]+red[6]+red[7]);
        atomicAdd(&g_qfilm[m], red[8]+red[9]+red[10]+red[11]);
    }
}

// single-compute filter: register-buffered survivors, per-molecule buckets.
#define FT 512
#define FPT 4
__global__ void k_filter(const int* idx_i, const int* idx_j, const float* offsets,
                         const float* r0_ij, const float* n_ij){
    __shared__ unsigned s_cnt[NMOL], s_base[NMOL];
    int tid = threadIdx.x;
    if (tid < NMOL) s_cnt[tid] = 0u;
    int p0 = blockIdx.x*(FT*FPT) + tid;
    int pi[FPT], pj[FPT];
    float ox[FPT], oy[FPT], oz[FPT];
#pragma unroll
    for (int k = 0; k < FPT; ++k){
        int p = p0 + k*FT;
        pi[k] = idx_i[p]; pj[k] = idx_j[p];
        ox[k] = offsets[3*p+0]; oy[k] = offsets[3*p+1]; oz[k] = offsets[3*p+2];
    }
    float4 xi[FPT], xj[FPT];
#pragma unroll
    for (int k = 0; k < FPT; ++k){ xi[k] = g_X[pi[k]]; xj[k] = g_X[pj[k]]; }
    __syncthreads();
    float rx[FPT], ry[FPT], rz[FPT], d2[FPT];
    bool sv[FPT];
    unsigned rk[FPT];
#pragma unroll
    for (int k = 0; k < FPT; ++k){
        rx[k] = xj[k].x - xi[k].x + ox[k];
        ry[k] = xj[k].y - xi[k].y + oy[k];
        rz[k] = xj[k].z - xi[k].z + oz[k];
        d2[k] = rx[k]*rx[k] + ry[k]*ry[k] + rz[k]*rz[k];
        sv[k] = d2[k] < CUTOFF_C*CUTOFF_C;
        if (sv[k]) rk[k] = atomicAdd(&s_cnt[pi[k] >> LOG2PERM], 1u);
    }
    __syncthreads();
    if (tid < NMOL){
        unsigned c = s_cnt[tid];
        s_base[tid] = c ? atomicAdd(&g_cnt[tid], c) : 0u;
    }
    __syncthreads();
#pragma unroll
    for (int k = 0; k < FPT; ++k) if (sv[k]){
        int p = p0 + k*FT;
        int m = pi[k] >> LOG2PERM;
        unsigned slot = s_base[m] + rk[k];
        if (slot < CAPM){
            unsigned fi = g_filmb[pi[k]], fj = g_filmb[pj[k]];
            unsigned pk = (unsigned)(pi[k] & 4095) | ((unsigned)(pj[k] & 4095) << 12) | (fi << 24) | (fj << 25);
            int o = m*CAPM + (int)slot;
            g_recA[o] = make_float4(__uint_as_float(pk), rx[k], ry[k], rz[k]);
            g_recB[o] = make_float4(r0_ij[p], n_ij[p], xi[k].w*xj[k].w, d2[k]);
        }
    }
}

// one pass computes S (all atoms) and S_film (q*film weights)
__global__ void k_sfac(){
    int bid = blockIdx.x;
    int m = bid / NKK;
    float4 kvc = g_kvc[bid];
    if (kvc.w == 0.f) return;
    float sre = 0.f, sim = 0.f, fre = 0.f, fim = 0.f;
    for (int a = threadIdx.x; a < PERM; a += blockDim.x){
        int n = (m << LOG2PERM) + a;
        float4 x = g_X[n];
        float qf = g_qf[n];
        float th = kvc.x*x.x + kvc.y*x.y + kvc.z*x.z;
        float s, c;
        __sincosf(th, &s, &c);
        sre += x.w*c; sim += x.w*s;
        fre += qf*c;  fim += qf*s;
    }
    sre = waveReduce(sre); sim = waveReduce(sim);
    fre = waveReduce(fre); fim = waveReduce(fim);
    __shared__ float red[16];
    int lane = threadIdx.x & 63, w = threadIdx.x >> 6;
    if (!lane){ red[w] = sre; red[4+w] = sim; red[8+w] = fre; red[12+w] = fim; }
    __syncthreads();
    if (threadIdx.x == 0){
        g_S[bid]  = make_float2(red[0]+red[1]+red[2]+red[3],   red[4]+red[5]+red[6]+red[7]);
        g_Sf[bid] = make_float2(red[8]+red[9]+red[10]+red[11], red[12]+red[13]+red[14]+red[15]);
    }
}

// 32 blocks per molecule; each block accumulates its record slice into a
// private LDS force tile, then writes the tile as a partial (no global atomics).
template<int PASS>
__launch_bounds__(512)
__global__ void k_pairs_part(){
    __shared__ float s_acc[PERM*3];    // 48 KB
    __shared__ float redE[16];
    int m = blockIdx.x >> 5;
    int b = blockIdx.x & (BPM-1);
    int tid = threadIdx.x;
    for (int w = tid; w < PERM*3; w += 512) s_acc[w] = 0.f;
    float Fx = 0.f, Fy = 0.f, Fz = 0.f;
    if (PASS){ Fx = g_Fm[m][0]; Fy = g_Fm[m][1]; Fz = g_Fm[m][2]; }
    float FRC = g_FRC;
    __syncthreads();
    int nrec = (int)g_cnt[m]; if (nrec > CAPM) nrec = CAPM;
    int per = (nrec + BPM - 1) >> 5;
    int rlo = b*per;
    int rhi = rlo + per; if (rhi > nrec) rhi = nrec;
    float er_sum = 0.f, eb_sum = 0.f;
    for (int r = rlo + tid; r < rhi; r += 512){
        float4 A = g_recA[m*CAPM + r];
        float4 B = g_recB[m*CAPM + r];
        unsigned pk = __float_as_uint(A.x);
        int il = pk & 4095, jl = (pk >> 12) & 4095;
        float rx = A.y, ry = A.z, rz = A.w;
        float r0 = B.x, nij = B.y, qq = B.z, d2 = B.w;
        float d = sqrtf(d2);
        float inv_d = 1.f/d;
        float Bc = fabsf(qq)*__expf((nij - 1.f)*__logf(r0))/nij;
        float er = erfcf(SQRT_ALPHA_C*d);
        float expt = __expf(-ALPHA_C*d2);
        float dmn = __expf(-nij*__logf(d));               // d^-n
        float fp = -ACONST_C*expt*inv_d - er*inv_d*inv_d; // f'(d)
        float Up = 0.5f*KE_C*(qq*fp - Bc*nij*dmn*inv_d);  // U'(d)
        float gx, gy, gz;
        if (PASS == 0){
            er_sum += qq*(er*inv_d - FRC);
            eb_sum += Bc*(dmn - __expf(-nij*LN_CUTOFF_C));
            float sc = Up*inv_d;
            gx = sc*rx; gy = sc*ry; gz = sc*rz;
        } else {
            float fpp = ACONST_C*expt*(2.f*ALPHA_C + 2.f*inv_d*inv_d) + 2.f*er*inv_d*inv_d*inv_d;
            float Upp = 0.5f*KE_C*(qq*fpp + Bc*nij*(nij+1.f)*dmn*inv_d*inv_d);
            float dsg = (float)((pk >> 25) & 1) - (float)((pk >> 24) & 1);  // fj - fi
            float dvx = dsg*Fx, dvy = dsg*Fy, dvz = dsg*Fz;
            float ddot = (rx*dvx + ry*dvy + rz*dvz)*inv_d;
            float ui = Up*inv_d;
            float c1 = (Upp - ui)*ddot*inv_d;
            gx = c1*rx + ui*dvx;
            gy = c1*ry + ui*dvy;
            gz = c1*rz + ui*dvz;
        }
        atomicAdd(&s_acc[jl*3+0],  gx); atomicAdd(&s_acc[jl*3+1],  gy); atomicAdd(&s_acc[jl*3+2],  gz);
        atomicAdd(&s_acc[il*3+0], -gx); atomicAdd(&s_acc[il*3+1], -gy); atomicAdd(&s_acc[il*3+2], -gz);
    }
    __syncthreads();
    float4* dst = (float4*)(g_part + (size_t)(m*BPM + b)*(PERM*3));
    const float4* src = (const float4*)s_acc;
    for (int w = tid; w < PERM*3/4; w += 512) dst[w] = src[w];
    if (PASS == 0){
        er_sum = waveReduce(er_sum); eb_sum = waveReduce(eb_sum);
        int lane = tid & 63, wv = tid >> 6;
        if (!lane){ redE[wv] = er_sum; redE[8+wv] = eb_sum; }
        __syncthreads();
        if (tid == 0){
            float a = 0.f, bb = 0.f;
            for (int k2 = 0; k2 < 8; ++k2){ a += redE[k2]; bb += redE[8+k2]; }
            atomicAdd(&g_yreal[m], a);
            atomicAdd(&g_yborn[m], bb);
        }
    }
}

// sum the 32 partials per molecule -> pair forces (overwrite, no zeroing needed)
template<int PASS>
__global__ void k_greduce(){
    int m = blockIdx.x / 24;
    int w = (blockIdx.x % 24)*512 + threadIdx.x;
    const float* src = g_part + (size_t)m*BPM*(PERM*3) + w;
    float s = 0.f;
#pragma unroll
    for (int b = 0; b < BPM; ++b) s += src[(size_t)b*(PERM*3)];
    float* T = PASS ? g_HVf : g_Gf;
    T[m*(PERM*3) + w] = s;
}

// reciprocal gradient via phasor recurrence; PASS1 uses Sd = (k.Fm)*i*S_film
#define RG_BLOCK 128
template<int PASS>
__global__ void k_recip_grad(){
    __shared__ float2 s_u[NKK];
    __shared__ float2 s_v[NKK];
    __shared__ float  s_b[6];
    int tid = threadIdx.x;
    int n = blockIdx.x*RG_BLOCK + tid;
    int m = n >> LOG2PERM;
    if (tid < 6) s_b[tid] = g_recipM[m][tid];
    float Fx = 0.f, Fy = 0.f, Fz = 0.f;
    if (PASS){ Fx = g_Fm[m][0]; Fy = g_Fm[m][1]; Fz = g_Fm[m][2]; }
    for (int a = tid; a < NKK; a += RG_BLOCK){
        int kx = a/25 - 12, ky = a%25 - 12;
        int ixo = (kx >= 0) ? kx : 12 - kx;
        int iyo = (ky >= 0) ? ky : 12 - ky;
        int src = m*NKK + ixo*25 + iyo;
        float4 kv = g_kvc[src];
        float c = kv.w;
        float2 S = g_S[src];
        s_u[a] = make_float2(c*S.x, c*S.y);
        if (PASS){
            float2 Sf = g_Sf[src];
            float kvF = kv.x*Fx + kv.y*Fy + kv.z*Fz;
            s_v[a] = make_float2(-c*kvF*Sf.y, c*kvF*Sf.x);
        }
    }
    __syncthreads();
    float4 x4 = g_X[n];
    float b1x=s_b[0], b1y=s_b[1], b1z=s_b[2];
    float b2x=s_b[3], b2y=s_b[4], b2z=s_b[5];
    float th1 = b1x*x4.x + b1y*x4.y + b1z*x4.z;
    float th2 = b2x*x4.x + b2y*x4.y + b2z*x4.z;
    float E1s, E1c, E2s, E2c, Ps, Pc, Q0s, Q0c;
    sincosf(th1, &E1s, &E1c);
    sincosf(th2, &E2s, &E2c);
    sincosf(-12.f*th1, &Ps, &Pc);
    sincosf(-12.f*th2, &Q0s, &Q0c);
    float phi1 = 0.f, phi2 = 0.f;
    if (PASS){
        float film = (float)g_filmb[n];
        phi1 = film*(b1x*Fx + b1y*Fy + b1z*Fz);
        phi2 = film*(b2x*Fx + b2y*Fy + b2z*Fz);
    }
    float A1 = 0.f, A2 = 0.f;
    int a = 0;
    for (int kxi = 0; kxi < 25; ++kxi){
        float kx = (float)(kxi - 12);
        float pc = Pc*Q0c - Ps*Q0s;
        float ps = Pc*Q0s + Ps*Q0c;
        for (int kyi = 0; kyi < 25; ++kyi, ++a){
            float ky = (float)(kyi - 12);
            float2 u = s_u[a];
            float t;
            if (PASS == 0){
                t = u.y*pc - u.x*ps;
            } else {
                float2 v = s_v[a];
                float thd = kx*phi1 + ky*phi2;
                t = v.y*pc - v.x*ps - (u.y*ps + u.x*pc)*thd;
            }
            A1 += t*kx; A2 += t*ky;
            float npc = pc*E2c - ps*E2s;
            float nps = pc*E2s + ps*E2c;
            pc = npc; ps = nps;
        }
        float nPc = Pc*E1c - Ps*E1s;
        float nPs = Pc*E1s + Ps*E1c;
        Pc = nPc; Ps = nPs;
    }
    float gx = A1*b1x + A2*b2x;
    float gy = A1*b1y + A2*b2y;
    float gz = A1*b1z + A2*b2z;
    float sc = 2.f*KE_C*x4.w;
    float slab = 2.f*KE_C*g_C2*x4.w*(PASS ? g_Dd : g_D);
    float* T = PASS ? g_HVf : g_Gf;
    int o = 3*n;
    T[o+0] += sc*gx;
    T[o+1] += sc*gy;
    T[o+2] += sc*gz + slab;
}

__global__ void k_reduce_F(){
    int m = blockIdx.x;
    float fx = 0.f, fy = 0.f, fz = 0.f;
    for (int a = threadIdx.x; a < PERM; a += blockDim.x){
        int n = (m << LOG2PERM) + a;
        float film = (float)g_filmb[n];
        int o = 3*n;
        fx -= film*g_Gf[o+0]; fy -= film*g_Gf[o+1]; fz -= film*g_Gf[o+2];
    }
    fx = waveReduce(fx); fy = waveReduce(fy); fz = waveReduce(fz);
    __shared__ float red[12];
    int lane = threadIdx.x & 63, w = threadIdx.x >> 6;
    if (!lane){ red[w] = fx; red[4+w] = fy; red[8+w] = fz; }
    __syncthreads();
    if (threadIdx.x == 0){
        float FX = red[0]+red[1]+red[2]+red[3];
        float FY = red[4]+red[5]+red[6]+red[7];
        float FZ = red[8]+red[9]+red[10]+red[11];
        g_Fm[m][0] = FX; g_Fm[m][1] = FY; g_Fm[m][2] = FZ;
        g_norm2[m] = FX*FX + FY*FY + FZ*FZ;
        atomicAdd(&g_Dd, FZ*g_qfilm[m]);   // Dd = sum_m Fz * sum(q*film)
    }
}

// final outputs; also folds the reciprocal-energy reduction
__global__ void k_final(float* out){
    int m = blockIdx.x;
    float ax = 0.f, ay = 0.f, az = 0.f, acc = 0.f;
    for (int a = threadIdx.x; a < PERM; a += blockDim.x){
        int n = (m << LOG2PERM) + a;
        float film = (float)g_filmb[n];
        int o = 3*n;
        ax += film*g_HVf[o+0]; ay += film*g_HVf[o+1]; az += film*g_HVf[o+2];
    }
    for (int kk = threadIdx.x; kk < NKK; kk += blockDim.x){
        float4 kvc = g_kvc[m*NKK + kk];
        float2 S = g_S[m*NKK + kk];
        acc += kvc.w*(S.x*S.x + S.y*S.y);
    }
    ax = waveReduce(ax); ay = waveReduce(ay); az = waveReduce(az); acc = waveReduce(acc);
    __shared__ float red[16];
    int lane = threadIdx.x & 63, w = threadIdx.x >> 6;
    if (!lane){ red[w] = ax; red[4+w] = ay; red[8+w] = az; red[12+w] = acc; }
    __syncthreads();
    if (threadIdx.x == 0){
        float AX = red[0]+red[1]+red[2]+red[3];
        float AY = red[4]+red[5]+red[6]+red[7];
        float AZ = red[8]+red[9]+red[10]+red[11];
        float yew = red[12]+red[13]+red[14]+red[15];
        out[32 + 3*m + 0] = -2.f*AX;
        out[32 + 3*m + 1] = -2.f*AY;
        out[32 + 3*m + 2] = -2.f*AZ;
        float D = g_D;
        float yslab = KE_C*(TWO_PI_C/g_vbox[m])*D*D;
        float yrecip = KE_C*(yew - SELF_C*g_self[m]) + yslab;
        float yr = 0.5f*KE_C*g_yreal[m];
        float yb = 0.5f*KE_C*g_yborn[m];
        float yc = yr + yrecip;
        out[0  + m] = yc + yb;
        out[8  + m] = yc;
        out[16 + m] = yb;
        out[24 + m] = g_norm2[m];
    }
}

extern "C" void kernel_launch(void* const* d_in, const int* in_sizes, int n_in,
                              void* d_out, int out_size, void* d_ws, size_t ws_size,
                              hipStream_t stream){
    const float* q       = (const float*)d_in[0];
    const float* R       = (const float*)d_in[1];
    const float* shift   = (const float*)d_in[2];
    const float* cell    = (const float*)d_in[3];
    const float* offsets = (const float*)d_in[4];
    const float* r0_ij   = (const float*)d_in[5];
    const float* n_ij    = (const float*)d_in[6];
    const int*   idx_i   = (const int*)d_in[7];
    const int*   idx_j   = (const int*)d_in[8];
    const int*   is_film = (const int*)d_in[10];
    float* out = (float*)d_out;

    k_prep<<<dim3(1), dim3(64), 0, stream>>>(cell);
    k_kvec<<<dim3((NMOL*NKK + 255)/256), dim3(256), 0, stream>>>();
    k_shift<<<dim3(NATOM/256), dim3(256), 0, stream>>>(q, R, shift, is_film);
    k_filter<<<dim3(NPAIR/(FT*FPT)), dim3(FT), 0, stream>>>(idx_i, idx_j, offsets, r0_ij, n_ij);
    k_sfac<<<dim3(NMOL*NKK), dim3(256), 0, stream>>>();
    k_pairs_part<0><<<dim3(NMOL*BPM), dim3(512), 0, stream>>>();
    k_greduce<0><<<dim3(NMOL*24), dim3(512), 0, stream>>>();
    k_recip_grad<0><<<dim3(NATOM/RG_BLOCK), dim3(RG_BLOCK), 0, stream>>>();
    k_reduce_F<<<dim3(NMOL), dim3(256), 0, stream>>>();
    k_pairs_part<1><<<dim3(NMOL*BPM), dim3(512), 0, stream>>>();
    k_greduce<1><<<dim3(NMOL*24), dim3(512), 0, stream>>>();
    k_recip_grad<1><<<dim3(NATOM/RG_BLOCK), dim3(RG_BLOCK), 0, stream>>>();
    k_final<<<dim3(NMOL), dim3(256), 0, stream>>>(out);
}

// Round 6
// 144.894 us; speedup vs baseline: 3.3023x; 1.1484x over previous
//
#include <hip/hip_runtime.h>
#include <math.h>

#define NATOM 32768
#define NMOL 8
#define PERM 4096
#define LOG2PERM 12
#define NPAIR 2097152
#define NKKH 312          // half k-grid: kx=0,ky=1..12 (12) + kx=1..12,ky=-12..12 (300)
#define CAPM 32768        // per-molecule record capacity (~26k expected)
#define BPM 32            // pair blocks per molecule

#define KE_C 14.3996f
#define ALPHA_C 0.3f
#define CUTOFF_C 6.0f
#define SQRT_ALPHA_C 0.5477225575051661f   // sqrt(0.3)
#define ACONST_C 0.6180387232371366f       // 2*sqrt(alpha/pi)
#define SELF_C 0.3090193616185683f         // sqrt(alpha/pi)
#define TWO_PI_C 6.283185307179586f
#define LN_CUTOFF_C 1.791759469228055f     // ln(6)

// persistent device state
__device__ float4 g_X[NATOM];            // x,y,z,q
__device__ float4 g_TH[NATOM];           // th1,th2,q,q*film
__device__ unsigned char g_filmb[NATOM];
__device__ float4 g_kvch[NMOL*NKKH];     // kvx,kvy,kvz,coef (compact half grid)
__device__ float2 g_S[NMOL*NKKH];        // structure factor (all atoms)
__device__ float2 g_Sf[NMOL*NKKH];       // structure factor (q*film weights)
__device__ float4 g_recA[NMOL*CAPM];     // packed ij+film, rx, ry, rz
__device__ float4 g_recB[NMOL*CAPM];     // r0, n, qq, d2
__device__ unsigned g_cnt[NMOL];
__device__ float g_recipM[NMOL][9];
__device__ float g_vbox[NMOL];
__device__ float g_self[NMOL], g_qfilm[NMOL];
__device__ float g_yreal[NMOL], g_yborn[NMOL];
__device__ float g_SGp[NMOL][3], g_SGr[NMOL][3];   // sum film*G (pair, recip)
__device__ float g_SHp[NMOL][3], g_SHr[NMOL][3];   // sum film*HV (pair, recip)
__device__ float g_Fm[NMOL][3], g_norm2[NMOL];
__device__ float g_D, g_Dd, g_C2, g_FRC;

__device__ __forceinline__ float waveReduce(float v){
#pragma unroll
    for (int off = 32; off > 0; off >>= 1) v += __shfl_down(v, off, 64);
    return v;
}

// prep + zero + compact k-vector table (1 block)
__global__ void k_prepkvec(const float* cell){
    int tid = threadIdx.x;
    if (tid < NMOL){
        g_cnt[tid] = 0u; g_self[tid] = 0.f; g_qfilm[tid] = 0.f;
        g_yreal[tid] = 0.f; g_yborn[tid] = 0.f;
        for (int c = 0; c < 3; ++c){
            g_SGp[tid][c] = 0.f; g_SGr[tid][c] = 0.f;
            g_SHp[tid][c] = 0.f; g_SHr[tid][c] = 0.f;
        }
        const float* c = cell + 9*tid;
        float a=c[0],b=c[1],cc=c[2],d=c[3],e=c[4],f=c[5],g=c[6],h=c[7],i=c[8];
        float det = a*(e*i - f*h) - b*(d*i - f*g) + cc*(d*h - e*g);
        float inv = 1.f/det;
        float i00=(e*i-f*h)*inv,  i01=(cc*h-b*i)*inv, i02=(b*f-cc*e)*inv;
        float i10=(f*g-d*i)*inv,  i11=(a*i-cc*g)*inv, i12=(cc*d-a*f)*inv;
        float i20=(d*h-e*g)*inv,  i21=(b*g-a*h)*inv,  i22=(a*e-b*d)*inv;
        g_recipM[tid][0]=TWO_PI_C*i00; g_recipM[tid][1]=TWO_PI_C*i10; g_recipM[tid][2]=TWO_PI_C*i20;
        g_recipM[tid][3]=TWO_PI_C*i01; g_recipM[tid][4]=TWO_PI_C*i11; g_recipM[tid][5]=TWO_PI_C*i21;
        g_recipM[tid][6]=TWO_PI_C*i02; g_recipM[tid][7]=TWO_PI_C*i12; g_recipM[tid][8]=TWO_PI_C*i22;
        g_vbox[tid] = fabsf(det);
    }
    if (tid == 0){ g_D = 0.f; g_Dd = 0.f; }
    __syncthreads();
    if (tid == 0){
        float c2 = 0.f;
        for (int mm = 0; mm < NMOL; ++mm) c2 += TWO_PI_C/g_vbox[mm];
        g_C2 = c2;
        g_FRC = (float)(erfc(sqrt(0.3)*6.0)/6.0);
    }
    for (int id = tid; id < NMOL*NKKH; id += blockDim.x){
        int m = id / NKKH, h = id % NKKH;
        int kx, ky;
        if (h < 12){ kx = 0; ky = h + 1; }
        else { int t = h - 12; kx = t/25 + 1; ky = t%25 - 12; }
        float fkx = (float)kx, fky = (float)ky;
        float nrm = fkx*fkx + fky*fky;
        float kvx = fkx*g_recipM[m][0] + fky*g_recipM[m][3];
        float kvy = fkx*g_recipM[m][1] + fky*g_recipM[m][4];
        float kvz = fkx*g_recipM[m][2] + fky*g_recipM[m][5];
        float coef = 0.f;
        if (nrm <= 146.f){
            float ksq = kvx*kvx + kvy*kvy + kvz*kvz;
            coef = (TWO_PI_C/g_vbox[m]) * expf(-0.25f*ksq/ALPHA_C) / ksq;
        }
        g_kvch[id] = make_float4(kvx, kvy, kvz, coef);
    }
}

__global__ void k_shift(const float* q, const float* R, const float* shift, const int* is_film){
    int n = blockIdx.x*blockDim.x + threadIdx.x;
    int m = n >> LOG2PERM;
    int film = is_film[n];
    float qn = q[n];
    float x = R[3*n+0], y = R[3*n+1], z = R[3*n+2];
    if (film){ x += shift[3*m+0]; y += shift[3*m+1]; z += shift[3*m+2]; }
    g_X[n] = make_float4(x, y, z, qn);
    g_filmb[n] = (unsigned char)film;
    float qf = film ? qn : 0.f;
    float th1 = g_recipM[m][0]*x + g_recipM[m][1]*y + g_recipM[m][2]*z;
    float th2 = g_recipM[m][3]*x + g_recipM[m][4]*y + g_recipM[m][5]*z;
    g_TH[n] = make_float4(th1, th2, qn, qf);
    float vD = waveReduce(qn*z);
    float vS = waveReduce(qn*qn);
    float vQ = waveReduce(qf);
    __shared__ float red[12];
    int lane = threadIdx.x & 63, w = threadIdx.x >> 6;
    if (!lane){ red[w] = vD; red[4+w] = vS; red[8+w] = vQ; }
    __syncthreads();
    if (threadIdx.x == 0){
        unsafeAtomicAdd(&g_D, red[0]+red[1]+red[2]+red[3]);
        unsafeAtomicAdd(&g_self[m], red[4]+red[5]+red[6]+red[7]);
        unsafeAtomicAdd(&g_qfilm[m], red[8]+red[9]+red[10]+red[11]);
    }
}

// single-pass filter, deep MLP: 8 pairs/thread, all loads issued up front.
#define FT 256
#define FPT 8
__global__ void k_filter(const int* idx_i, const int* idx_j, const float* offsets,
                         const float* r0_ij, const float* n_ij){
    __shared__ unsigned s_cnt[NMOL], s_base[NMOL];
    int tid = threadIdx.x;
    if (tid < NMOL) s_cnt[tid] = 0u;
    int p0 = blockIdx.x*(FT*FPT) + tid;
    int pi[FPT], pj[FPT];
    float ox[FPT], oy[FPT], oz[FPT], r0v[FPT], nv[FPT];
#pragma unroll
    for (int k = 0; k < FPT; ++k){
        int p = p0 + k*FT;
        pi[k] = idx_i[p]; pj[k] = idx_j[p];
    }
#pragma unroll
    for (int k = 0; k < FPT; ++k){
        int p = p0 + k*FT;
        ox[k] = offsets[3*p+0]; oy[k] = offsets[3*p+1]; oz[k] = offsets[3*p+2];
        r0v[k] = r0_ij[p]; nv[k] = n_ij[p];
    }
    float4 xi[FPT], xj[FPT];
#pragma unroll
    for (int k = 0; k < FPT; ++k){ xi[k] = g_X[pi[k]]; xj[k] = g_X[pj[k]]; }
    __syncthreads();
    float rx[FPT], ry[FPT], rz[FPT], d2[FPT];
    bool sv[FPT];
    unsigned rk[FPT];
#pragma unroll
    for (int k = 0; k < FPT; ++k){
        rx[k] = xj[k].x - xi[k].x + ox[k];
        ry[k] = xj[k].y - xi[k].y + oy[k];
        rz[k] = xj[k].z - xi[k].z + oz[k];
        d2[k] = rx[k]*rx[k] + ry[k]*ry[k] + rz[k]*rz[k];
        sv[k] = d2[k] < CUTOFF_C*CUTOFF_C;
        if (sv[k]) rk[k] = atomicAdd(&s_cnt[pi[k] >> LOG2PERM], 1u);
    }
    __syncthreads();
    if (tid < NMOL){
        unsigned c = s_cnt[tid];
        s_base[tid] = c ? atomicAdd(&g_cnt[tid], c) : 0u;
    }
    __syncthreads();
#pragma unroll
    for (int k = 0; k < FPT; ++k) if (sv[k]){
        int m = pi[k] >> LOG2PERM;
        unsigned slot = s_base[m] + rk[k];
        if (slot < CAPM){
            unsigned fi = g_filmb[pi[k]], fj = g_filmb[pj[k]];
            unsigned pk = (unsigned)(pi[k] & 4095) | ((unsigned)(pj[k] & 4095) << 12) | (fi << 24) | (fj << 25);
            int o = m*CAPM + (int)slot;
            g_recA[o] = make_float4(__uint_as_float(pk), rx[k], ry[k], rz[k]);
            g_recB[o] = make_float4(r0v[k], nv[k], xi[k].w*xj[k].w, d2[k]);
        }
    }
}

// structure factors over the half grid via phasor recurrence.
// block = (molecule, chunk of <=8 consecutive ky at fixed kx). 50 chunks/molecule.
__launch_bounds__(256)
__global__ void k_sfac(){
    int m = blockIdx.x / 50, c = blockIdx.x % 50;
    int kx, ky0, h0, len;
    if (c < 2){ kx = 0; ky0 = 1 + 8*c; h0 = 8*c; len = c ? 4 : 8; }
    else { int t = c - 2; kx = t/4 + 1; int s4 = t%4; ky0 = -12 + 8*s4; h0 = 12 + (kx-1)*25 + 8*s4; len = (s4==3) ? 1 : 8; }
    float fkx = (float)kx, fky0 = (float)ky0;
    int tid = threadIdx.x;
    int base = m << LOG2PERM;
    float aR[8], aI[8], bR[8], bI[8];
#pragma unroll
    for (int e = 0; e < 8; ++e){ aR[e]=0.f; aI[e]=0.f; bR[e]=0.f; bI[e]=0.f; }
    for (int a = 0; a < 16; ++a){
        float4 th = g_TH[base + tid + a*256];
        float s, cc, s2, c2;
        sincosf(fkx*th.x + fky0*th.y, &s, &cc);
        sincosf(th.y, &s2, &c2);
        float qv = th.z, qf = th.w;
#pragma unroll
        for (int e = 0; e < 8; ++e){
            aR[e] += qv*cc; aI[e] += qv*s;
            bR[e] += qf*cc; bI[e] += qf*s;
            float nc = cc*c2 - s*s2;
            float ns = cc*s2 + s*c2;
            cc = nc; s = ns;
        }
    }
    __shared__ float s_red[128];
    int lane = tid & 63, wid = tid >> 6;
#pragma unroll
    for (int e = 0; e < 8; ++e){
        float v0 = waveReduce(aR[e]), v1 = waveReduce(aI[e]);
        float v2 = waveReduce(bR[e]), v3 = waveReduce(bI[e]);
        if (!lane){
            s_red[(e*4+0)*4+wid] = v0; s_red[(e*4+1)*4+wid] = v1;
            s_red[(e*4+2)*4+wid] = v2; s_red[(e*4+3)*4+wid] = v3;
        }
    }
    __syncthreads();
    if (tid < 32){
        float v = s_red[tid*4+0]+s_red[tid*4+1]+s_red[tid*4+2]+s_red[tid*4+3];
        int e = tid >> 2, comp = tid & 3;
        if (e < len){
            int idx = m*NKKH + h0 + e;
            if (comp == 0) g_S[idx].x = v;
            else if (comp == 1) g_S[idx].y = v;
            else if (comp == 2) g_Sf[idx].x = v;
            else g_Sf[idx].y = v;
        }
    }
}

// pair sweep: 32 blocks/molecule, private LDS force tile, then film-weighted
// reduction straight to 3 global atomics (per-atom forces never hit memory).
template<int PASS>
__launch_bounds__(512)
__global__ void k_pairs_part(){
    __shared__ float s_acc[PERM*3];    // 48 KB
    __shared__ float sred[24];
    __shared__ float redE[16];
    int m = blockIdx.x >> 5;
    int b = blockIdx.x & (BPM-1);
    int tid = threadIdx.x;
    float4* z4 = (float4*)s_acc;
    for (int w = tid; w < PERM*3/4; w += 512) z4[w] = make_float4(0.f,0.f,0.f,0.f);
    float Fx = 0.f, Fy = 0.f, Fz = 0.f;
    if (PASS){ Fx = g_Fm[m][0]; Fy = g_Fm[m][1]; Fz = g_Fm[m][2]; }
    float FRC = g_FRC;
    __syncthreads();
    int nrec = (int)g_cnt[m]; if (nrec > CAPM) nrec = CAPM;
    int per = (nrec + BPM - 1) >> 5;
    int rlo = b*per;
    int rhi = rlo + per; if (rhi > nrec) rhi = nrec;
    float er_sum = 0.f, eb_sum = 0.f;
    for (int r = rlo + tid; r < rhi; r += 512){
        float4 A = g_recA[m*CAPM + r];
        float4 B = g_recB[m*CAPM + r];
        unsigned pk = __float_as_uint(A.x);
        int il = pk & 4095, jl = (pk >> 12) & 4095;
        float rx = A.y, ry = A.z, rz = A.w;
        float r0 = B.x, nij = B.y, qq = B.z, d2 = B.w;
        float d = sqrtf(d2);
        float inv_d = 1.f/d;
        float Bc = fabsf(qq)*__expf((nij - 1.f)*__logf(r0))/nij;
        float er = erfcf(SQRT_ALPHA_C*d);
        float expt = __expf(-ALPHA_C*d2);
        float dmn = __expf(-nij*__logf(d));               // d^-n
        float fp = -ACONST_C*expt*inv_d - er*inv_d*inv_d; // f'(d)
        float Up = 0.5f*KE_C*(qq*fp - Bc*nij*dmn*inv_d);  // U'(d)
        float gx, gy, gz;
        if (PASS == 0){
            er_sum += qq*(er*inv_d - FRC);
            eb_sum += Bc*(dmn - __expf(-nij*LN_CUTOFF_C));
            float sc = Up*inv_d;
            gx = sc*rx; gy = sc*ry; gz = sc*rz;
        } else {
            float fpp = ACONST_C*expt*(2.f*ALPHA_C + 2.f*inv_d*inv_d) + 2.f*er*inv_d*inv_d*inv_d;
            float Upp = 0.5f*KE_C*(qq*fpp + Bc*nij*(nij+1.f)*dmn*inv_d*inv_d);
            float dsg = (float)((pk >> 25) & 1) - (float)((pk >> 24) & 1);  // fj - fi
            float dvx = dsg*Fx, dvy = dsg*Fy, dvz = dsg*Fz;
            float ddot = (rx*dvx + ry*dvy + rz*dvz)*inv_d;
            float ui = Up*inv_d;
            float c1 = (Upp - ui)*ddot*inv_d;
            gx = c1*rx + ui*dvx;
            gy = c1*ry + ui*dvy;
            gz = c1*rz + ui*dvz;
        }
        atomicAdd(&s_acc[jl*3+0],  gx); atomicAdd(&s_acc[jl*3+1],  gy); atomicAdd(&s_acc[jl*3+2],  gz);
        atomicAdd(&s_acc[il*3+0], -gx); atomicAdd(&s_acc[il*3+1], -gy); atomicAdd(&s_acc[il*3+2], -gz);
    }
    __syncthreads();
    float fx = 0.f, fy = 0.f, fz = 0.f;
    int base = m << LOG2PERM;
    for (int a = tid; a < PERM; a += 512){
        float film = (float)g_filmb[base+a];
        fx += film*s_acc[a*3+0]; fy += film*s_acc[a*3+1]; fz += film*s_acc[a*3+2];
    }
    fx = waveReduce(fx); fy = waveReduce(fy); fz = waveReduce(fz);
    int lane = tid & 63, wv = tid >> 6;
    if (PASS == 0){
        er_sum = waveReduce(er_sum); eb_sum = waveReduce(eb_sum);
        if (!lane){ redE[wv] = er_sum; redE[8+wv] = eb_sum; }
    }
    if (!lane){ sred[wv] = fx; sred[8+wv] = fy; sred[16+wv] = fz; }
    __syncthreads();
    if (tid == 0){
        float FX=0.f, FY=0.f, FZ=0.f;
        for (int k2 = 0; k2 < 8; ++k2){ FX += sred[k2]; FY += sred[8+k2]; FZ += sred[16+k2]; }
        float* dst = PASS ? g_SHp[m] : g_SGp[m];
        unsafeAtomicAdd(&dst[0], FX);
        unsafeAtomicAdd(&dst[1], FY);
        unsafeAtomicAdd(&dst[2], FZ);
        if (PASS == 0){
            float a = 0.f, bb = 0.f;
            for (int k2 = 0; k2 < 8; ++k2){ a += redE[k2]; bb += redE[8+k2]; }
            unsafeAtomicAdd(&g_yreal[m], a);
            unsafeAtomicAdd(&g_yborn[m], bb);
        }
    }
}

// reciprocal gradient, half grid x2, per-atom result stays in registers;
// only the film-weighted molecule sum leaves the block.
#define RG_BLOCK 128
template<int PASS>
__global__ void k_recip_grad(){
    __shared__ float2 s_u[NKKH];
    __shared__ float2 s_v[NKKH];
    __shared__ float  s_b[6];
    __shared__ float  sred[6];
    int tid = threadIdx.x;
    int n = blockIdx.x*RG_BLOCK + tid;
    int m = n >> LOG2PERM;
    if (tid < 6) s_b[tid] = g_recipM[m][tid];
    float Fx = 0.f, Fy = 0.f, Fz = 0.f;
    if (PASS){ Fx = g_Fm[m][0]; Fy = g_Fm[m][1]; Fz = g_Fm[m][2]; }
    for (int h = tid; h < NKKH; h += RG_BLOCK){
        float4 kv = g_kvch[m*NKKH + h];
        float2 S = g_S[m*NKKH + h];
        s_u[h] = make_float2(kv.w*S.x, kv.w*S.y);
        if (PASS){
            float2 Sf = g_Sf[m*NKKH + h];
            float kvF = kv.x*Fx + kv.y*Fy + kv.z*Fz;
            s_v[h] = make_float2(-kv.w*kvF*Sf.y, kv.w*kvF*Sf.x);
        }
    }
    __syncthreads();
    float4 th4 = g_TH[n];
    float th1 = th4.x, th2 = th4.y, qn = th4.z;
    float film = (float)g_filmb[n];
    float b1x=s_b[0], b1y=s_b[1], b1z=s_b[2];
    float b2x=s_b[3], b2y=s_b[4], b2z=s_b[5];
    float E1s, E1c, E2s, E2c, Q0s, Q0c;
    sincosf(th1, &E1s, &E1c);
    sincosf(th2, &E2s, &E2c);
    sincosf(-12.f*th2, &Q0s, &Q0c);
    float phi1 = 0.f, phi2 = 0.f;
    if (PASS){
        phi1 = film*(b1x*Fx + b1y*Fy + b1z*Fz);
        phi2 = film*(b2x*Fx + b2y*Fy + b2z*Fz);
    }
    float A1 = 0.f, A2 = 0.f;
    int h = 0;
    {   // kx = 0, ky = 1..12
        float pc = E2c, ps = E2s;
        for (int kyi = 1; kyi <= 12; ++kyi, ++h){
            float2 u = s_u[h];
            float t;
            if (PASS == 0) t = u.y*pc - u.x*ps;
            else {
                float2 v = s_v[h];
                float thd = (float)kyi*phi2;
                t = v.y*pc - v.x*ps - (u.y*ps + u.x*pc)*thd;
            }
            A2 += t*(float)kyi;
            float npc = pc*E2c - ps*E2s;
            float nps = pc*E2s + ps*E2c;
            pc = npc; ps = nps;
        }
    }
    float Pc = E1c, Ps = E1s;   // e^{i*kx*th1}, kx starts at 1
    for (int kxi = 1; kxi <= 12; ++kxi){
        float fkx = (float)kxi;
        float pc = Pc*Q0c - Ps*Q0s;
        float ps = Pc*Q0s + Ps*Q0c;
        for (int kyi = 0; kyi < 25; ++kyi, ++h){
            float fky = (float)(kyi - 12);
            float2 u = s_u[h];
            float t;
            if (PASS == 0) t = u.y*pc - u.x*ps;
            else {
                float2 v = s_v[h];
                float thd = fkx*phi1 + fky*phi2;
                t = v.y*pc - v.x*ps - (u.y*ps + u.x*pc)*thd;
            }
            A1 += t*fkx; A2 += t*fky;
            float npc = pc*E2c - ps*E2s;
            float nps = pc*E2s + ps*E2c;
            pc = npc; ps = nps;
        }
        float nPc = Pc*E1c - Ps*E1s;
        float nPs = Pc*E1s + Ps*E1c;
        Pc = nPc; Ps = nPs;
    }
    A1 *= 2.f; A2 *= 2.f;   // +k/-k symmetry
    float sc = 2.f*KE_C*qn;
    float slab = 2.f*KE_C*g_C2*qn*(PASS ? g_Dd : g_D);
    float sx = film*(sc*(A1*b1x + A2*b2x));
    float sy = film*(sc*(A1*b1y + A2*b2y));
    float sz = film*(sc*(A1*b1z + A2*b2z) + slab);
    sx = waveReduce(sx); sy = waveReduce(sy); sz = waveReduce(sz);
    int lane = tid & 63, wv = tid >> 6;
    if (!lane){ sred[wv] = sx; sred[2+wv] = sy; sred[4+wv] = sz; }
    __syncthreads();
    if (tid == 0){
        float* dst = PASS ? g_SHr[m] : g_SGr[m];
        unsafeAtomicAdd(&dst[0], sred[0]+sred[1]);
        unsafeAtomicAdd(&dst[1], sred[2]+sred[3]);
        unsafeAtomicAdd(&dst[2], sred[4]+sred[5]);
    }
}

// tiny: F_m, norm2, Dd
__global__ void k_post(){
    int tid = threadIdx.x;
    if (tid < NMOL){
        float fx = -(g_SGp[tid][0] + g_SGr[tid][0]);
        float fy = -(g_SGp[tid][1] + g_SGr[tid][1]);
        float fz = -(g_SGp[tid][2] + g_SGr[tid][2]);
        g_Fm[tid][0] = fx; g_Fm[tid][1] = fy; g_Fm[tid][2] = fz;
        g_norm2[tid] = fx*fx + fy*fy + fz*fz;
    }
    __syncthreads();
    if (tid == 0){
        float dd = 0.f;
        for (int mm = 0; mm < NMOL; ++mm) dd += g_Fm[mm][2]*g_qfilm[mm];
        g_Dd = dd;
    }
}

// energies + all outputs (one block per molecule)
__global__ void k_final(float* out){
    int m = blockIdx.x;
    float acc = 0.f;
    for (int h = threadIdx.x; h < NKKH; h += blockDim.x){
        float4 kv = g_kvch[m*NKKH + h];
        float2 S = g_S[m*NKKH + h];
        acc += kv.w*(S.x*S.x + S.y*S.y);
    }
    acc = waveReduce(acc);
    __shared__ float red[4];
    int lane = threadIdx.x & 63, w = threadIdx.x >> 6;
    if (!lane) red[w] = acc;
    __syncthreads();
    if (threadIdx.x == 0){
        float yew = 2.f*(red[0]+red[1]+red[2]+red[3]);
        float D = g_D;
        float yslab = KE_C*(TWO_PI_C/g_vbox[m])*D*D;
        float yrecip = KE_C*(yew - SELF_C*g_self[m]) + yslab;
        float yr = 0.5f*KE_C*g_yreal[m];
        float yb = 0.5f*KE_C*g_yborn[m];
        float yc = yr + yrecip;
        out[0  + m] = yc + yb;
        out[8  + m] = yc;
        out[16 + m] = yb;
        out[24 + m] = g_norm2[m];
        out[32 + 3*m + 0] = -2.f*(g_SHp[m][0] + g_SHr[m][0]);
        out[32 + 3*m + 1] = -2.f*(g_SHp[m][1] + g_SHr[m][1]);
        out[32 + 3*m + 2] = -2.f*(g_SHp[m][2] + g_SHr[m][2]);
    }
}

extern "C" void kernel_launch(void* const* d_in, const int* in_sizes, int n_in,
                              void* d_out, int out_size, void* d_ws, size_t ws_size,
                              hipStream_t stream){
    const float* q       = (const float*)d_in[0];
    const float* R       = (const float*)d_in[1];
    const float* shift   = (const float*)d_in[2];
    const float* cell    = (const float*)d_in[3];
    const float* offsets = (const float*)d_in[4];
    const float* r0_ij   = (const float*)d_in[5];
    const float* n_ij    = (const float*)d_in[6];
    const int*   idx_i   = (const int*)d_in[7];
    const int*   idx_j   = (const int*)d_in[8];
    const int*   is_film = (const int*)d_in[10];
    float* out = (float*)d_out;

    k_prepkvec<<<dim3(1), dim3(1024), 0, stream>>>(cell);
    k_shift<<<dim3(NATOM/256), dim3(256), 0, stream>>>(q, R, shift, is_film);
    k_filter<<<dim3(NPAIR/(FT*FPT)), dim3(FT), 0, stream>>>(idx_i, idx_j, offsets, r0_ij, n_ij);
    k_sfac<<<dim3(NMOL*50), dim3(256), 0, stream>>>();
    k_pairs_part<0><<<dim3(NMOL*BPM), dim3(512), 0, stream>>>();
    k_recip_grad<0><<<dim3(NATOM/RG_BLOCK), dim3(RG_BLOCK), 0, stream>>>();
    k_post<<<dim3(1), dim3(64), 0, stream>>>();
    k_pairs_part<1><<<dim3(NMOL*BPM), dim3(512), 0, stream>>>();
    k_recip_grad<1><<<dim3(NATOM/RG_BLOCK), dim3(RG_BLOCK), 0, stream>>>();
    k_final<<<dim3(NMOL), dim3(256), 0, stream>>>(out);
}

// Round 7
// 115.942 us; speedup vs baseline: 4.1269x; 1.2497x over previous
//
#include <hip/hip_runtime.h>
#include <math.h>

#define NATOM 32768
#define NMOL 8
#define PERM 4096
#define LOG2PERM 12
#define NPAIR 2097152
#define NKKH 312          // half k-grid: kx=0,ky=1..12 (12) + kx=1..12,ky=-12..12 (300)
#define CAPM 32768        // per-molecule record capacity (~26k expected)
#define BPM 32            // pair blocks per molecule
#define NFILT 2048        // filter blocks
#define PPB 1024          // pairs per filter block
#define NSFB (NMOL*50)    // sfac blocks

#define KE_C 14.3996f
#define ALPHA_C 0.3f
#define CUTOFF_C 6.0f
#define SQRT_ALPHA_C 0.5477225575051661f   // sqrt(0.3)
#define ACONST_C 0.6180387232371366f       // 2*sqrt(alpha/pi)
#define SELF_C 0.3090193616185683f         // sqrt(alpha/pi)
#define TWO_PI_C 6.283185307179586f
#define LN_CUTOFF_C 1.791759469228055f     // ln(6)

// persistent device state. Accumulators (cnt, D, self, qfilm, yreal, yborn,
// SG*, SH*) follow the zero-at-end protocol: zeroed at module load (.bss) and
// re-zeroed by k_final after use, so every launch starts from zeros.
__device__ float4 g_X[NATOM];            // x,y,z,q
__device__ float4 g_TH[NATOM];           // th1,th2,q,q*film
__device__ unsigned char g_filmb[NATOM];
__device__ float4 g_kvch[NMOL*NKKH];     // kvx,kvy,kvz,coef (compact half grid)
__device__ float2 g_S[NMOL*NKKH];        // structure factor (all atoms)
__device__ float2 g_Sf[NMOL*NKKH];       // structure factor (q*film weights)
__device__ float4 g_recA[NMOL*CAPM];     // packed ij+film, rx, ry, rz
__device__ float4 g_recB[NMOL*CAPM];     // r0, n, qq, d2
__device__ unsigned g_cnt[NMOL];
__device__ float g_recipM[NMOL][9];
__device__ float g_vbox[NMOL];
__device__ float g_self[NMOL], g_qfilm[NMOL];
__device__ float g_yreal[NMOL], g_yborn[NMOL];
__device__ float g_SGp[NMOL][3], g_SGr[NMOL][3];   // sum film*G (pair, recip)
__device__ float g_SHp[NMOL][3], g_SHr[NMOL][3];   // sum film*HV (pair, recip)
__device__ float g_D, g_C2, g_FRC;

__device__ __forceinline__ float waveReduce(float v){
#pragma unroll
    for (int off = 32; off > 0; off >>= 1) v += __shfl_down(v, off, 64);
    return v;
}

__device__ __forceinline__ void invCell(const float* c, float rm[9], float& vb){
    float a=c[0],b=c[1],cc=c[2],d=c[3],e=c[4],f=c[5],g=c[6],h=c[7],i=c[8];
    float det = a*(e*i - f*h) - b*(d*i - f*g) + cc*(d*h - e*g);
    float inv = 1.f/det;
    rm[0]=TWO_PI_C*(e*i-f*h)*inv;  rm[1]=TWO_PI_C*(f*g-d*i)*inv;  rm[2]=TWO_PI_C*(d*h-e*g)*inv;
    rm[3]=TWO_PI_C*(cc*h-b*i)*inv; rm[4]=TWO_PI_C*(a*i-cc*g)*inv; rm[5]=TWO_PI_C*(b*g-a*h)*inv;
    rm[6]=TWO_PI_C*(b*f-cc*e)*inv; rm[7]=TWO_PI_C*(cc*d-a*f)*inv; rm[8]=TWO_PI_C*(a*e-b*d)*inv;
    vb = fabsf(det);
}

// block 0: k-vector table + constants; blocks 1..128: position shift + TH + sums
__global__ __launch_bounds__(256) void k_init(const float* cell, const float* q,
                                              const float* R, const float* shift,
                                              const int* is_film){
    __shared__ float s_rm[NMOL][9];
    __shared__ float s_vb[NMOL];
    __shared__ float red[12];
    int tid = threadIdx.x;
    if (tid < NMOL){
        float rm[9], vb;
        invCell(cell + 9*tid, rm, vb);
#pragma unroll
        for (int k = 0; k < 9; ++k) s_rm[tid][k] = rm[k];
        s_vb[tid] = vb;
    }
    __syncthreads();
    if (blockIdx.x == 0){
        if (tid < NMOL){
#pragma unroll
            for (int k = 0; k < 9; ++k) g_recipM[tid][k] = s_rm[tid][k];
            g_vbox[tid] = s_vb[tid];
        }
        if (tid == 0){
            float c2 = 0.f;
            for (int mm = 0; mm < NMOL; ++mm) c2 += TWO_PI_C/s_vb[mm];
            g_C2 = c2;
            g_FRC = (float)(erfc(sqrt(0.3)*6.0)/6.0);
        }
        for (int id = tid; id < NMOL*NKKH; id += 256){
            int m = id / NKKH, h = id % NKKH;
            int kx, ky;
            if (h < 12){ kx = 0; ky = h + 1; }
            else { int t = h - 12; kx = t/25 + 1; ky = t%25 - 12; }
            float fkx = (float)kx, fky = (float)ky;
            float nrm = fkx*fkx + fky*fky;
            float kvx = fkx*s_rm[m][0] + fky*s_rm[m][3];
            float kvy = fkx*s_rm[m][1] + fky*s_rm[m][4];
            float kvz = fkx*s_rm[m][2] + fky*s_rm[m][5];
            float coef = 0.f;
            if (nrm <= 146.f){
                float ksq = kvx*kvx + kvy*kvy + kvz*kvz;
                coef = (TWO_PI_C/s_vb[m]) * expf(-0.25f*ksq/ALPHA_C) / ksq;
            }
            g_kvch[id] = make_float4(kvx, kvy, kvz, coef);
        }
    } else {
        int n = (blockIdx.x - 1)*256 + tid;
        int m = n >> LOG2PERM;
        int film = is_film[n];
        float qn = q[n];
        float x = R[3*n+0], y = R[3*n+1], z = R[3*n+2];
        if (film){ x += shift[3*m+0]; y += shift[3*m+1]; z += shift[3*m+2]; }
        g_X[n] = make_float4(x, y, z, qn);
        g_filmb[n] = (unsigned char)film;
        float qf = film ? qn : 0.f;
        float th1 = s_rm[m][0]*x + s_rm[m][1]*y + s_rm[m][2]*z;
        float th2 = s_rm[m][3]*x + s_rm[m][4]*y + s_rm[m][5]*z;
        g_TH[n] = make_float4(th1, th2, qn, qf);
        float vD = waveReduce(qn*z);
        float vS = waveReduce(qn*qn);
        float vQ = waveReduce(qf);
        int lane = tid & 63, w = tid >> 6;
        if (!lane){ red[w] = vD; red[4+w] = vS; red[8+w] = vQ; }
        __syncthreads();
        if (tid == 0){
            unsafeAtomicAdd(&g_D, red[0]+red[1]+red[2]+red[3]);
            unsafeAtomicAdd(&g_self[m], red[4]+red[5]+red[6]+red[7]);
            unsafeAtomicAdd(&g_qfilm[m], red[8]+red[9]+red[10]+red[11]);
        }
    }
}

// blocks [0,NFILT): pair filter (LDS-staged offsets, 4 pairs/thread)
// blocks [NFILT, NFILT+NSFB): structure factors via phasor recurrence
__global__ __launch_bounds__(256) void k_fsf(const int* idx_i, const int* idx_j,
                                             const float* offsets,
                                             const float* r0_ij, const float* n_ij){
    __shared__ float s_off[PPB*3];     // 12 KB; aliased by sfac role
    __shared__ unsigned s_cnt[NMOL], s_base[NMOL];
    int tid = threadIdx.x;
    if (blockIdx.x < NFILT){
        int p0 = blockIdx.x*PPB;
        const float4* osrc = (const float4*)(offsets + 3*p0);
        float4* odst = (float4*)s_off;
#pragma unroll
        for (int w = 0; w < 3; ++w) odst[tid + w*256] = osrc[tid + w*256];
        if (tid < NMOL) s_cnt[tid] = 0u;
        int pi[4], pj[4];
        float r0v[4], nv[4];
#pragma unroll
        for (int k = 0; k < 4; ++k){
            int p = p0 + k*256 + tid;
            pi[k] = idx_i[p]; pj[k] = idx_j[p];
        }
#pragma unroll
        for (int k = 0; k < 4; ++k){
            int p = p0 + k*256 + tid;
            r0v[k] = r0_ij[p]; nv[k] = n_ij[p];
        }
        float4 xi[4], xj[4];
#pragma unroll
        for (int k = 0; k < 4; ++k){ xi[k] = g_X[pi[k]]; xj[k] = g_X[pj[k]]; }
        __syncthreads();
        float rx[4], ry[4], rz[4], d2[4];
        bool sv[4];
        unsigned rk[4];
#pragma unroll
        for (int k = 0; k < 4; ++k){
            int lp = k*256 + tid;
            rx[k] = xj[k].x - xi[k].x + s_off[3*lp+0];
            ry[k] = xj[k].y - xi[k].y + s_off[3*lp+1];
            rz[k] = xj[k].z - xi[k].z + s_off[3*lp+2];
            d2[k] = rx[k]*rx[k] + ry[k]*ry[k] + rz[k]*rz[k];
            sv[k] = d2[k] < CUTOFF_C*CUTOFF_C;
            if (sv[k]) rk[k] = atomicAdd(&s_cnt[pi[k] >> LOG2PERM], 1u);
        }
        __syncthreads();
        if (tid < NMOL){
            unsigned c = s_cnt[tid];
            s_base[tid] = c ? atomicAdd(&g_cnt[tid], c) : 0u;
        }
        __syncthreads();
#pragma unroll
        for (int k = 0; k < 4; ++k) if (sv[k]){
            int m = pi[k] >> LOG2PERM;
            unsigned slot = s_base[m] + rk[k];
            if (slot < CAPM){
                unsigned fi = g_filmb[pi[k]], fj = g_filmb[pj[k]];
                unsigned pk = (unsigned)(pi[k] & 4095) | ((unsigned)(pj[k] & 4095) << 12) | (fi << 24) | (fj << 25);
                int o = m*CAPM + (int)slot;
                g_recA[o] = make_float4(__uint_as_float(pk), rx[k], ry[k], rz[k]);
                g_recB[o] = make_float4(r0v[k], nv[k], xi[k].w*xj[k].w, d2[k]);
            }
        }
    } else {
        int sb = blockIdx.x - NFILT;
        int m = sb / 50, c = sb % 50;
        int kx, ky0, h0, len;
        if (c < 2){ kx = 0; ky0 = 1 + 8*c; h0 = 8*c; len = c ? 4 : 8; }
        else { int t = c - 2; kx = t/4 + 1; int s4 = t%4; ky0 = -12 + 8*s4; h0 = 12 + (kx-1)*25 + 8*s4; len = (s4==3) ? 1 : 8; }
        float fkx = (float)kx, fky0 = (float)ky0;
        int base = m << LOG2PERM;
        float aR[8], aI[8], bR[8], bI[8];
#pragma unroll
        for (int e = 0; e < 8; ++e){ aR[e]=0.f; aI[e]=0.f; bR[e]=0.f; bI[e]=0.f; }
        for (int a = 0; a < 16; ++a){
            float4 th = g_TH[base + tid + a*256];
            float s, cc, s2, c2;
            sincosf(fkx*th.x + fky0*th.y, &s, &cc);
            sincosf(th.y, &s2, &c2);
            float qv = th.z, qf = th.w;
#pragma unroll
            for (int e = 0; e < 8; ++e){
                aR[e] += qv*cc; aI[e] += qv*s;
                bR[e] += qf*cc; bI[e] += qf*s;
                float nc = cc*c2 - s*s2;
                float ns = cc*s2 + s*c2;
                cc = nc; s = ns;
            }
        }
        float* s_red = s_off;
        int lane = tid & 63, wid = tid >> 6;
#pragma unroll
        for (int e = 0; e < 8; ++e){
            float v0 = waveReduce(aR[e]), v1 = waveReduce(aI[e]);
            float v2 = waveReduce(bR[e]), v3 = waveReduce(bI[e]);
            if (!lane){
                s_red[(e*4+0)*4+wid] = v0; s_red[(e*4+1)*4+wid] = v1;
                s_red[(e*4+2)*4+wid] = v2; s_red[(e*4+3)*4+wid] = v3;
            }
        }
        __syncthreads();
        if (tid < 32){
            float v = s_red[tid*4+0]+s_red[tid*4+1]+s_red[tid*4+2]+s_red[tid*4+3];
            int e = tid >> 2, comp = tid & 3;
            if (e < len){
                int idx = m*NKKH + h0 + e;
                if (comp == 0) g_S[idx].x = v;
                else if (comp == 1) g_S[idx].y = v;
                else if (comp == 2) g_Sf[idx].x = v;
                else g_Sf[idx].y = v;
            }
        }
    }
}

// blocks [0,256): pair sweep (LDS force tile -> film-weighted 3-float atomic)
// blocks [256,320): reciprocal gradient (phasor recurrence, register result)
template<int PASS>
__launch_bounds__(512)
__global__ void k_pass(){
    __shared__ float s_mem[PERM*3];    // 48 KB (pairs tile / sfac staging alias)
    __shared__ float sred[24];
    __shared__ float redE[16];
    __shared__ float s_b[6];
    int tid = threadIdx.x;
    if (blockIdx.x < NMOL*BPM){
        int m = blockIdx.x >> 5;
        int b = blockIdx.x & (BPM-1);
        float* s_acc = s_mem;
        float4* z4 = (float4*)s_acc;
        for (int w = tid; w < PERM*3/4; w += 512) z4[w] = make_float4(0.f,0.f,0.f,0.f);
        float Fx = 0.f, Fy = 0.f, Fz = 0.f;
        if (PASS){
            Fx = -(g_SGp[m][0] + g_SGr[m][0]);
            Fy = -(g_SGp[m][1] + g_SGr[m][1]);
            Fz = -(g_SGp[m][2] + g_SGr[m][2]);
        }
        float FRC = g_FRC;
        __syncthreads();
        int nrec = (int)g_cnt[m]; if (nrec > CAPM) nrec = CAPM;
        int per = (nrec + BPM - 1) >> 5;
        int rlo = b*per;
        int rhi = rlo + per; if (rhi > nrec) rhi = nrec;
        float er_sum = 0.f, eb_sum = 0.f;
        for (int r = rlo + tid; r < rhi; r += 512){
            float4 A = g_recA[m*CAPM + r];
            float4 B = g_recB[m*CAPM + r];
            unsigned pk = __float_as_uint(A.x);
            int il = pk & 4095, jl = (pk >> 12) & 4095;
            float rx = A.y, ry = A.z, rz = A.w;
            float r0 = B.x, nij = B.y, qq = B.z, d2 = B.w;
            float d = sqrtf(d2);
            float inv_d = 1.f/d;
            float Bc = fabsf(qq)*__expf((nij - 1.f)*__logf(r0))/nij;
            float er = erfcf(SQRT_ALPHA_C*d);
            float expt = __expf(-ALPHA_C*d2);
            float dmn = __expf(-nij*__logf(d));               // d^-n
            float fp = -ACONST_C*expt*inv_d - er*inv_d*inv_d; // f'(d)
            float Up = 0.5f*KE_C*(qq*fp - Bc*nij*dmn*inv_d);  // U'(d)
            float gx, gy, gz;
            if (PASS == 0){
                er_sum += qq*(er*inv_d - FRC);
                eb_sum += Bc*(dmn - __expf(-nij*LN_CUTOFF_C));
                float sc = Up*inv_d;
                gx = sc*rx; gy = sc*ry; gz = sc*rz;
            } else {
                float fpp = ACONST_C*expt*(2.f*ALPHA_C + 2.f*inv_d*inv_d) + 2.f*er*inv_d*inv_d*inv_d;
                float Upp = 0.5f*KE_C*(qq*fpp + Bc*nij*(nij+1.f)*dmn*inv_d*inv_d);
                float dsg = (float)((pk >> 25) & 1) - (float)((pk >> 24) & 1);  // fj - fi
                float dvx = dsg*Fx, dvy = dsg*Fy, dvz = dsg*Fz;
                float ddot = (rx*dvx + ry*dvy + rz*dvz)*inv_d;
                float ui = Up*inv_d;
                float c1 = (Upp - ui)*ddot*inv_d;
                gx = c1*rx + ui*dvx;
                gy = c1*ry + ui*dvy;
                gz = c1*rz + ui*dvz;
            }
            atomicAdd(&s_acc[jl*3+0],  gx); atomicAdd(&s_acc[jl*3+1],  gy); atomicAdd(&s_acc[jl*3+2],  gz);
            atomicAdd(&s_acc[il*3+0], -gx); atomicAdd(&s_acc[il*3+1], -gy); atomicAdd(&s_acc[il*3+2], -gz);
        }
        __syncthreads();
        float fx = 0.f, fy = 0.f, fz = 0.f;
        int base = m << LOG2PERM;
        for (int a = tid; a < PERM; a += 512){
            float film = (float)g_filmb[base+a];
            fx += film*s_acc[a*3+0]; fy += film*s_acc[a*3+1]; fz += film*s_acc[a*3+2];
        }
        fx = waveReduce(fx); fy = waveReduce(fy); fz = waveReduce(fz);
        int lane = tid & 63, wv = tid >> 6;
        if (PASS == 0){
            er_sum = waveReduce(er_sum); eb_sum = waveReduce(eb_sum);
            if (!lane){ redE[wv] = er_sum; redE[8+wv] = eb_sum; }
        }
        if (!lane){ sred[wv] = fx; sred[8+wv] = fy; sred[16+wv] = fz; }
        __syncthreads();
        if (tid == 0){
            float FX=0.f, FY=0.f, FZ=0.f;
            for (int k2 = 0; k2 < 8; ++k2){ FX += sred[k2]; FY += sred[8+k2]; FZ += sred[16+k2]; }
            float* dst = PASS ? g_SHp[m] : g_SGp[m];
            unsafeAtomicAdd(&dst[0], FX);
            unsafeAtomicAdd(&dst[1], FY);
            unsafeAtomicAdd(&dst[2], FZ);
            if (PASS == 0){
                float a = 0.f, bb = 0.f;
                for (int k2 = 0; k2 < 8; ++k2){ a += redE[k2]; bb += redE[8+k2]; }
                unsafeAtomicAdd(&g_yreal[m], a);
                unsafeAtomicAdd(&g_yborn[m], bb);
            }
        }
    } else {
        int rb = blockIdx.x - NMOL*BPM;
        int n = rb*512 + tid;
        int m = n >> LOG2PERM;
        float2* s_u = (float2*)s_mem;
        float2* s_v = (float2*)(s_mem + 2*NKKH);
        if (tid < 6) s_b[tid] = g_recipM[m][tid];
        float Fx = 0.f, Fy = 0.f, Fz = 0.f, DD;
        if (PASS){
            Fx = -(g_SGp[m][0] + g_SGr[m][0]);
            Fy = -(g_SGp[m][1] + g_SGr[m][1]);
            Fz = -(g_SGp[m][2] + g_SGr[m][2]);
            float dd = 0.f;
            for (int mm = 0; mm < NMOL; ++mm)
                dd += -(g_SGp[mm][2] + g_SGr[mm][2])*g_qfilm[mm];
            DD = dd;
        } else {
            DD = g_D;
        }
        for (int h = tid; h < NKKH; h += 512){
            float4 kv = g_kvch[m*NKKH + h];
            float2 S = g_S[m*NKKH + h];
            s_u[h] = make_float2(kv.w*S.x, kv.w*S.y);
            if (PASS){
                float2 Sf = g_Sf[m*NKKH + h];
                float kvF = kv.x*Fx + kv.y*Fy + kv.z*Fz;
                s_v[h] = make_float2(-kv.w*kvF*Sf.y, kv.w*kvF*Sf.x);
            }
        }
        __syncthreads();
        float4 th4 = g_TH[n];
        float th1 = th4.x, th2 = th4.y, qn = th4.z;
        float film = (float)g_filmb[n];
        float b1x=s_b[0], b1y=s_b[1], b1z=s_b[2];
        float b2x=s_b[3], b2y=s_b[4], b2z=s_b[5];
        float E1s, E1c, E2s, E2c, Q0s, Q0c;
        sincosf(th1, &E1s, &E1c);
        sincosf(th2, &E2s, &E2c);
        sincosf(-12.f*th2, &Q0s, &Q0c);
        float phi1 = 0.f, phi2 = 0.f;
        if (PASS){
            phi1 = film*(b1x*Fx + b1y*Fy + b1z*Fz);
            phi2 = film*(b2x*Fx + b2y*Fy + b2z*Fz);
        }
        float A1 = 0.f, A2 = 0.f;
        int h = 0;
        {   // kx = 0, ky = 1..12
            float pc = E2c, ps = E2s;
            for (int kyi = 1; kyi <= 12; ++kyi, ++h){
                float2 u = s_u[h];
                float t;
                if (PASS == 0) t = u.y*pc - u.x*ps;
                else {
                    float2 v = s_v[h];
                    float thd = (float)kyi*phi2;
                    t = v.y*pc - v.x*ps - (u.y*ps + u.x*pc)*thd;
                }
                A2 += t*(float)kyi;
                float npc = pc*E2c - ps*E2s;
                float nps = pc*E2s + ps*E2c;
                pc = npc; ps = nps;
            }
        }
        float Pc = E1c, Ps = E1s;
        for (int kxi = 1; kxi <= 12; ++kxi){
            float fkx = (float)kxi;
            float pc = Pc*Q0c - Ps*Q0s;
            float ps = Pc*Q0s + Ps*Q0c;
            for (int kyi = 0; kyi < 25; ++kyi, ++h){
                float fky = (float)(kyi - 12);
                float2 u = s_u[h];
                float t;
                if (PASS == 0) t = u.y*pc - u.x*ps;
                else {
                    float2 v = s_v[h];
                    float thd = fkx*phi1 + fky*phi2;
                    t = v.y*pc - v.x*ps - (u.y*ps + u.x*pc)*thd;
                }
                A1 += t*fkx; A2 += t*fky;
                float npc = pc*E2c - ps*E2s;
                float nps = pc*E2s + ps*E2c;
                pc = npc; ps = nps;
            }
            float nPc = Pc*E1c - Ps*E1s;
            float nPs = Pc*E1s + Ps*E1c;
            Pc = nPc; Ps = nPs;
        }
        A1 *= 2.f; A2 *= 2.f;   // +k/-k symmetry
        float sc = 2.f*KE_C*qn;
        float slab = 2.f*KE_C*g_C2*qn*DD;
        float sx = film*(sc*(A1*b1x + A2*b2x));
        float sy = film*(sc*(A1*b1y + A2*b2y));
        float sz = film*(sc*(A1*b1z + A2*b2z) + slab);
        sx = waveReduce(sx); sy = waveReduce(sy); sz = waveReduce(sz);
        int lane = tid & 63, wv = tid >> 6;
        if (!lane){ sred[wv] = sx; sred[8+wv] = sy; sred[16+wv] = sz; }
        __syncthreads();
        if (tid == 0){
            float SX=0.f, SY=0.f, SZ=0.f;
            for (int k2 = 0; k2 < 8; ++k2){ SX += sred[k2]; SY += sred[8+k2]; SZ += sred[16+k2]; }
            float* dst = PASS ? g_SHr[m] : g_SGr[m];
            unsafeAtomicAdd(&dst[0], SX);
            unsafeAtomicAdd(&dst[1], SY);
            unsafeAtomicAdd(&dst[2], SZ);
        }
    }
}

// outputs + re-zero all accumulators for the next call (zero-at-end protocol)
__global__ __launch_bounds__(512) void k_final(float* out){
    int tid = threadIdx.x;
    int m = tid >> 6, lane = tid & 63;
    float acc = 0.f;
    for (int h = lane; h < NKKH; h += 64){
        float4 kv = g_kvch[m*NKKH + h];
        float2 S = g_S[m*NKKH + h];
        acc += kv.w*(S.x*S.x + S.y*S.y);
    }
    acc = waveReduce(acc);
    if (lane == 0){
        float yew = 2.f*acc;
        float D = g_D;
        float yslab = KE_C*(TWO_PI_C/g_vbox[m])*D*D;
        float yrecip = KE_C*(yew - SELF_C*g_self[m]) + yslab;
        float yr = 0.5f*KE_C*g_yreal[m];
        float yb = 0.5f*KE_C*g_yborn[m];
        float yc = yr + yrecip;
        float fx = -(g_SGp[m][0] + g_SGr[m][0]);
        float fy = -(g_SGp[m][1] + g_SGr[m][1]);
        float fz = -(g_SGp[m][2] + g_SGr[m][2]);
        out[0  + m] = yc + yb;
        out[8  + m] = yc;
        out[16 + m] = yb;
        out[24 + m] = fx*fx + fy*fy + fz*fz;
        out[32 + 3*m + 0] = -2.f*(g_SHp[m][0] + g_SHr[m][0]);
        out[32 + 3*m + 1] = -2.f*(g_SHp[m][1] + g_SHr[m][1]);
        out[32 + 3*m + 2] = -2.f*(g_SHp[m][2] + g_SHr[m][2]);
    }
    __syncthreads();
    if (tid < NMOL){
        g_cnt[tid] = 0u; g_self[tid] = 0.f; g_qfilm[tid] = 0.f;
        g_yreal[tid] = 0.f; g_yborn[tid] = 0.f;
#pragma unroll
        for (int c = 0; c < 3; ++c){
            g_SGp[tid][c] = 0.f; g_SGr[tid][c] = 0.f;
            g_SHp[tid][c] = 0.f; g_SHr[tid][c] = 0.f;
        }
    }
    if (tid == 0) g_D = 0.f;
}

extern "C" void kernel_launch(void* const* d_in, const int* in_sizes, int n_in,
                              void* d_out, int out_size, void* d_ws, size_t ws_size,
                              hipStream_t stream){
    const float* q       = (const float*)d_in[0];
    const float* R       = (const float*)d_in[1];
    const float* shift   = (const float*)d_in[2];
    const float* cell    = (const float*)d_in[3];
    const float* offsets = (const float*)d_in[4];
    const float* r0_ij   = (const float*)d_in[5];
    const float* n_ij    = (const float*)d_in[6];
    const int*   idx_i   = (const int*)d_in[7];
    const int*   idx_j   = (const int*)d_in[8];
    const int*   is_film = (const int*)d_in[10];
    float* out = (float*)d_out;

    k_init<<<dim3(1 + NATOM/256), dim3(256), 0, stream>>>(cell, q, R, shift, is_film);
    k_fsf<<<dim3(NFILT + NSFB), dim3(256), 0, stream>>>(idx_i, idx_j, offsets, r0_ij, n_ij);
    k_pass<0><<<dim3(NMOL*BPM + NATOM/512), dim3(512), 0, stream>>>();
    k_pass<1><<<dim3(NMOL*BPM + NATOM/512), dim3(512), 0, stream>>>();
    k_final<<<dim3(1), dim3(512), 0, stream>>>(out);
}

// Round 8
// 111.626 us; speedup vs baseline: 4.2865x; 1.0387x over previous
//
#include <hip/hip_runtime.h>
#include <math.h>

#define NATOM 32768
#define NMOL 8
#define PERM 4096
#define LOG2PERM 12
#define NPAIR 2097152
#define NKKH 312          // half k-grid: kx=0,ky=1..12 (12) + kx=1..12,ky=-12..12 (300)
#define CAPREC 393216     // compacted fi!=fj survivor records (~105k expected)
#define NFILT 2048        // filter blocks (1024 pairs each)
#define NSFB (NMOL*50)    // sfac blocks
#define PB1 256           // pass1 pair blocks
#define RB1 (NATOM/256)   // pass1 recip blocks

#define KE_C 14.3996f
#define ALPHA_C 0.3f
#define SQRT_ALPHA_C 0.5477225575051661f   // sqrt(0.3)
#define ACONST_C 0.6180387232371366f       // 2*sqrt(alpha/pi)
#define SELF_C 0.3090193616185683f         // sqrt(alpha/pi)
#define TWO_PI_C 6.283185307179586f
#define LN_CUTOFF_C 1.791759469228055f     // ln(6)

// persistent device state; accumulators follow zero-at-end protocol
// (.bss zero at load; k_final re-zeroes after use).
__device__ float4 g_X[NATOM];            // x,y,z,q
__device__ float4 g_TH[NATOM];           // th1,th2,q,q*film
__device__ unsigned char g_filmb[NATOM];
__device__ float4 g_kvch[NMOL*NKKH];     // kvx,kvy,kvz,coef
__device__ float2 g_S[NMOL*NKKH];        // structure factor (all atoms)
__device__ float2 g_Sf[NMOL*NKKH];       // structure factor (q*film)
__device__ float4 g_recA[CAPREC];        // rx, ry, rz, d2
__device__ float4 g_recB[CAPREC];        // r0, n, qq, m
__device__ int   g_nrec;
__device__ float g_recipM[NMOL][9];
__device__ float g_vbox[NMOL];
__device__ float g_self[NMOL], g_qfilm[NMOL];
__device__ float g_yreal[NMOL], g_yborn[NMOL];
__device__ float g_SG[NMOL][3];          // sum film*G (pair + recip)
__device__ float g_SH[NMOL][3];          // sum film*HV (pair + recip)
__device__ float g_D, g_C2, g_FRC;

__device__ __forceinline__ float waveReduce(float v){
#pragma unroll
    for (int off = 32; off > 0; off >>= 1) v += __shfl_down(v, off, 64);
    return v;
}

__device__ __forceinline__ void invCell(const float* c, float rm[9], float& vb){
    float a=c[0],b=c[1],cc=c[2],d=c[3],e=c[4],f=c[5],g=c[6],h=c[7],i=c[8];
    float det = a*(e*i - f*h) - b*(d*i - f*g) + cc*(d*h - e*g);
    float inv = 1.f/det;
    rm[0]=TWO_PI_C*(e*i-f*h)*inv;  rm[1]=TWO_PI_C*(f*g-d*i)*inv;  rm[2]=TWO_PI_C*(d*h-e*g)*inv;
    rm[3]=TWO_PI_C*(cc*h-b*i)*inv; rm[4]=TWO_PI_C*(a*i-cc*g)*inv; rm[5]=TWO_PI_C*(b*g-a*h)*inv;
    rm[6]=TWO_PI_C*(b*f-cc*e)*inv; rm[7]=TWO_PI_C*(cc*d-a*f)*inv; rm[8]=TWO_PI_C*(a*e-b*d)*inv;
    vb = fabsf(det);
}

// block 0: k-vector table + constants; blocks 1..128: shift + TH + scalar sums
__global__ __launch_bounds__(256) void k_init(const float* cell, const float* q,
                                              const float* R, const float* shift,
                                              const int* is_film){
    __shared__ float s_rm[NMOL][9];
    __shared__ float s_vb[NMOL];
    __shared__ float red[12];
    int tid = threadIdx.x;
    if (tid < NMOL){
        float rm[9], vb;
        invCell(cell + 9*tid, rm, vb);
#pragma unroll
        for (int k = 0; k < 9; ++k) s_rm[tid][k] = rm[k];
        s_vb[tid] = vb;
    }
    __syncthreads();
    if (blockIdx.x == 0){
        if (tid < NMOL){
#pragma unroll
            for (int k = 0; k < 9; ++k) g_recipM[tid][k] = s_rm[tid][k];
            g_vbox[tid] = s_vb[tid];
        }
        if (tid == 0){
            float c2 = 0.f;
            for (int mm = 0; mm < NMOL; ++mm) c2 += TWO_PI_C/s_vb[mm];
            g_C2 = c2;
            g_FRC = (float)(erfc(sqrt(0.3)*6.0)/6.0);
        }
        for (int id = tid; id < NMOL*NKKH; id += 256){
            int m = id / NKKH, h = id % NKKH;
            int kx, ky;
            if (h < 12){ kx = 0; ky = h + 1; }
            else { int t = h - 12; kx = t/25 + 1; ky = t%25 - 12; }
            float fkx = (float)kx, fky = (float)ky;
            float nrm = fkx*fkx + fky*fky;
            float kvx = fkx*s_rm[m][0] + fky*s_rm[m][3];
            float kvy = fkx*s_rm[m][1] + fky*s_rm[m][4];
            float kvz = fkx*s_rm[m][2] + fky*s_rm[m][5];
            float coef = 0.f;
            if (nrm <= 146.f){
                float ksq = kvx*kvx + kvy*kvy + kvz*kvz;
                coef = (TWO_PI_C/s_vb[m]) * expf(-0.25f*ksq/ALPHA_C) / ksq;
            }
            g_kvch[id] = make_float4(kvx, kvy, kvz, coef);
        }
    } else {
        int n = (blockIdx.x - 1)*256 + tid;
        int m = n >> LOG2PERM;
        int film = is_film[n];
        float qn = q[n];
        float x = R[3*n+0], y = R[3*n+1], z = R[3*n+2];
        if (film){ x += shift[3*m+0]; y += shift[3*m+1]; z += shift[3*m+2]; }
        g_X[n] = make_float4(x, y, z, qn);
        g_filmb[n] = (unsigned char)film;
        float qf = film ? qn : 0.f;
        float th1 = s_rm[m][0]*x + s_rm[m][1]*y + s_rm[m][2]*z;
        float th2 = s_rm[m][3]*x + s_rm[m][4]*y + s_rm[m][5]*z;
        g_TH[n] = make_float4(th1, th2, qn, qf);
        float vD = waveReduce(qn*z);
        float vS = waveReduce(qn*qn);
        float vQ = waveReduce(qf);
        int lane = tid & 63, w = tid >> 6;
        if (!lane){ red[w] = vD; red[4+w] = vS; red[8+w] = vQ; }
        __syncthreads();
        if (tid == 0){
            unsafeAtomicAdd(&g_D, red[0]+red[1]+red[2]+red[3]);
            unsafeAtomicAdd(&g_self[m], red[4]+red[5]+red[6]+red[7]);
            unsafeAtomicAdd(&g_qfilm[m], red[8]+red[9]+red[10]+red[11]);
        }
    }
}

// blocks [0,NFILT): filter + fused pass-0 pair sweep (vector loads,
//   register-sum via (fj-fi) trick, fi!=fj survivors compacted for pass 1)
// blocks [NFILT,NFILT+NSFB): structure factors via phasor recurrence
__global__ __launch_bounds__(256) void k_fsf(const int* idx_i, const int* idx_j,
                                             const float* offsets,
                                             const float* r0_ij, const float* n_ij){
    __shared__ float s_red[160];
    __shared__ float s_acc[NMOL*5];   // fx,fy,fz,ereal,eborn per molecule
    __shared__ int s_cnt, s_base;
    int tid = threadIdx.x;
    if (blockIdx.x < NFILT){
        if (tid < NMOL*5) s_acc[tid] = 0.f;
        if (tid == 0) s_cnt = 0;
        int p0 = blockIdx.x*1024 + tid*4;     // 4 consecutive pairs
        int4 ii = *(const int4*)(idx_i + p0);
        int4 jj = *(const int4*)(idx_j + p0);
        float4 r04 = *(const float4*)(r0_ij + p0);
        float4 n4  = *(const float4*)(n_ij + p0);
        const float4* ob = (const float4*)(offsets + 3*p0);
        float4 o0 = ob[0], o1 = ob[1], o2 = ob[2];
        int ia[4] = {ii.x, ii.y, ii.z, ii.w};
        int ja[4] = {jj.x, jj.y, jj.z, jj.w};
        float oxa[4] = {o0.x, o0.w, o1.z, o2.y};
        float oya[4] = {o0.y, o1.x, o1.w, o2.z};
        float oza[4] = {o0.z, o1.y, o2.x, o2.w};
        float r0a[4] = {r04.x, r04.y, r04.z, r04.w};
        float na[4]  = {n4.x, n4.y, n4.z, n4.w};
        float4 xi[4], xj[4];
        unsigned char fib[4], fjb[4];
#pragma unroll
        for (int k = 0; k < 4; ++k){
            xi[k] = g_X[ia[k]]; xj[k] = g_X[ja[k]];
            fib[k] = g_filmb[ia[k]]; fjb[k] = g_filmb[ja[k]];
        }
        float FRC = g_FRC;
        __syncthreads();
        float rsx[4], rsy[4], rsz[4], sd2[4], sr0[4], snn[4], sqq[4];
        int smm[4], rk[4];
        bool st[4];
#pragma unroll
        for (int k = 0; k < 4; ++k){
            st[k] = false;
            float rx = xj[k].x - xi[k].x + oxa[k];
            float ry = xj[k].y - xi[k].y + oya[k];
            float rz = xj[k].z - xi[k].z + oza[k];
            float d2v = rx*rx + ry*ry + rz*rz;
            if (d2v < 36.f){
                float d = sqrtf(d2v);
                float inv_d = 1.f/d;
                float qq = xi[k].w*xj[k].w;
                float nij = na[k], r0 = r0a[k];
                float Bc = fabsf(qq)*__expf((nij - 1.f)*__logf(r0))/nij;
                float er = erfcf(SQRT_ALPHA_C*d);
                float expt = __expf(-ALPHA_C*d2v);
                float dmn = __expf(-nij*__logf(d));
                float fp = -ACONST_C*expt*inv_d - er*inv_d*inv_d;
                float Up = 0.5f*KE_C*(qq*fp - Bc*nij*dmn*inv_d);
                int m = ia[k] >> LOG2PERM;
                atomicAdd(&s_acc[m*5+3], qq*(er*inv_d - FRC));
                atomicAdd(&s_acc[m*5+4], Bc*(dmn - __expf(-nij*LN_CUTOFF_C)));
                if (fib[k] != fjb[k]){
                    float fdiff = (float)fjb[k] - (float)fib[k];
                    float sc = Up*inv_d;
                    atomicAdd(&s_acc[m*5+0], fdiff*sc*rx);
                    atomicAdd(&s_acc[m*5+1], fdiff*sc*ry);
                    atomicAdd(&s_acc[m*5+2], fdiff*sc*rz);
                    rk[k] = atomicAdd(&s_cnt, 1);
                    st[k] = true;
                    rsx[k]=rx; rsy[k]=ry; rsz[k]=rz; sd2[k]=d2v;
                    sr0[k]=r0; snn[k]=nij; sqq[k]=qq; smm[k]=m;
                }
            }
        }
        __syncthreads();
        if (tid == 0) s_base = atomicAdd(&g_nrec, s_cnt);
        __syncthreads();
#pragma unroll
        for (int k = 0; k < 4; ++k) if (st[k]){
            int slot = s_base + rk[k];
            if (slot < CAPREC){
                g_recA[slot] = make_float4(rsx[k], rsy[k], rsz[k], sd2[k]);
                g_recB[slot] = make_float4(sr0[k], snn[k], sqq[k], (float)smm[k]);
            }
        }
        if (tid < NMOL*5){
            float v = s_acc[tid];
            if (v != 0.f){
                int m = tid/5, c = tid%5;
                if (c < 3) unsafeAtomicAdd(&g_SG[m][c], v);
                else if (c == 3) unsafeAtomicAdd(&g_yreal[m], v);
                else unsafeAtomicAdd(&g_yborn[m], v);
            }
        }
    } else {
        int sb = blockIdx.x - NFILT;
        int m = sb / 50, c = sb % 50;
        int kx, ky0, h0, len;
        if (c < 2){ kx = 0; ky0 = 1 + 8*c; h0 = 8*c; len = c ? 4 : 8; }
        else { int t = c - 2; kx = t/4 + 1; int s4 = t%4; ky0 = -12 + 8*s4; h0 = 12 + (kx-1)*25 + 8*s4; len = (s4==3) ? 1 : 8; }
        float fkx = (float)kx, fky0 = (float)ky0;
        int base = m << LOG2PERM;
        float aR[8], aI[8], bR[8], bI[8];
#pragma unroll
        for (int e = 0; e < 8; ++e){ aR[e]=0.f; aI[e]=0.f; bR[e]=0.f; bI[e]=0.f; }
        for (int a = 0; a < 16; ++a){
            float4 th = g_TH[base + tid + a*256];
            float s, cc, s2, c2;
            sincosf(fkx*th.x + fky0*th.y, &s, &cc);
            sincosf(th.y, &s2, &c2);
            float qv = th.z, qf = th.w;
#pragma unroll
            for (int e = 0; e < 8; ++e){
                aR[e] += qv*cc; aI[e] += qv*s;
                bR[e] += qf*cc; bI[e] += qf*s;
                float nc = cc*c2 - s*s2;
                float ns = cc*s2 + s*c2;
                cc = nc; s = ns;
            }
        }
        int lane = tid & 63, wid = tid >> 6;
#pragma unroll
        for (int e = 0; e < 8; ++e){
            float v0 = waveReduce(aR[e]), v1 = waveReduce(aI[e]);
            float v2 = waveReduce(bR[e]), v3 = waveReduce(bI[e]);
            if (!lane){
                s_red[(e*4+0)*4+wid] = v0; s_red[(e*4+1)*4+wid] = v1;
                s_red[(e*4+2)*4+wid] = v2; s_red[(e*4+3)*4+wid] = v3;
            }
        }
        __syncthreads();
        if (tid < 32){
            float v = s_red[tid*4+0]+s_red[tid*4+1]+s_red[tid*4+2]+s_red[tid*4+3];
            int e = tid >> 2, comp = tid & 3;
            if (e < len){
                int idx = m*NKKH + h0 + e;
                if (comp == 0) g_S[idx].x = v;
                else if (comp == 1) g_S[idx].y = v;
                else if (comp == 2) g_Sf[idx].x = v;
                else g_Sf[idx].y = v;
            }
        }
    }
}

// reciprocal gradient pass 0 (film-weighted sum only), phasor recurrence
__global__ __launch_bounds__(128) void k_rg0(){
    __shared__ float2 s_u[NKKH];
    __shared__ float  s_b[6];
    __shared__ float  sred[6];
    int tid = threadIdx.x;
    int n = blockIdx.x*128 + tid;
    int m = n >> LOG2PERM;
    if (tid < 6) s_b[tid] = g_recipM[m][tid];
    for (int h = tid; h < NKKH; h += 128){
        float4 kv = g_kvch[m*NKKH + h];
        float2 S = g_S[m*NKKH + h];
        s_u[h] = make_float2(kv.w*S.x, kv.w*S.y);
    }
    __syncthreads();
    float4 th4 = g_TH[n];
    float th1 = th4.x, th2 = th4.y, qn = th4.z;
    float film = (float)g_filmb[n];
    float E1s, E1c, E2s, E2c, Q0s, Q0c;
    sincosf(th1, &E1s, &E1c);
    sincosf(th2, &E2s, &E2c);
    sincosf(-12.f*th2, &Q0s, &Q0c);
    float A1 = 0.f, A2 = 0.f;
    int h = 0;
    {
        float pc = E2c, ps = E2s;
        for (int kyi = 1; kyi <= 12; ++kyi, ++h){
            float2 u = s_u[h];
            float t = u.y*pc - u.x*ps;
            A2 += t*(float)kyi;
            float npc = pc*E2c - ps*E2s;
            float nps = pc*E2s + ps*E2c;
            pc = npc; ps = nps;
        }
    }
    float Pc = E1c, Ps = E1s;
    for (int kxi = 1; kxi <= 12; ++kxi){
        float fkx = (float)kxi;
        float pc = Pc*Q0c - Ps*Q0s;
        float ps = Pc*Q0s + Ps*Q0c;
        for (int kyi = 0; kyi < 25; ++kyi, ++h){
            float fky = (float)(kyi - 12);
            float2 u = s_u[h];
            float t = u.y*pc - u.x*ps;
            A1 += t*fkx; A2 += t*fky;
            float npc = pc*E2c - ps*E2s;
            float nps = pc*E2s + ps*E2c;
            pc = npc; ps = nps;
        }
        float nPc = Pc*E1c - Ps*E1s;
        float nPs = Pc*E1s + Ps*E1c;
        Pc = nPc; Ps = nPs;
    }
    A1 *= 2.f; A2 *= 2.f;
    float b1x=s_b[0], b1y=s_b[1], b1z=s_b[2];
    float b2x=s_b[3], b2y=s_b[4], b2z=s_b[5];
    float sc = 2.f*KE_C*qn;
    float slab = 2.f*KE_C*g_C2*qn*g_D;
    float sx = film*(sc*(A1*b1x + A2*b2x));
    float sy = film*(sc*(A1*b1y + A2*b2y));
    float sz = film*(sc*(A1*b1z + A2*b2z) + slab);
    sx = waveReduce(sx); sy = waveReduce(sy); sz = waveReduce(sz);
    int lane = tid & 63, wv = tid >> 6;
    if (!lane){ sred[wv] = sx; sred[2+wv] = sy; sred[4+wv] = sz; }
    __syncthreads();
    if (tid == 0){
        unsafeAtomicAdd(&g_SG[m][0], sred[0]+sred[1]);
        unsafeAtomicAdd(&g_SG[m][1], sred[2]+sred[3]);
        unsafeAtomicAdd(&g_SG[m][2], sred[4]+sred[5]);
    }
}

// blocks [0,PB1): HVP pair sweep over compacted records (register compute)
// blocks [PB1,PB1+RB1): reciprocal gradient pass 1
__global__ __launch_bounds__(256) void k_pass1(){
    __shared__ float s_mem[4*NKKH];  // recip staging alias
    __shared__ float s_F[NMOL*3];
    __shared__ float s_hv[NMOL*3];
    __shared__ float s_b[6];
    __shared__ float sred[12];
    int tid = threadIdx.x;
    if (blockIdx.x < PB1){
        if (tid < NMOL*3){
            int m = tid/3, c = tid%3;
            s_F[tid] = -g_SG[m][c];
            s_hv[tid] = 0.f;
        }
        __syncthreads();
        int nrec = g_nrec; if (nrec > CAPREC) nrec = CAPREC;
        for (int r = blockIdx.x*256 + tid; r < nrec; r += PB1*256){
            float4 A = g_recA[r];
            float4 B = g_recB[r];
            int m = (int)B.w;
            float rx = A.x, ry = A.y, rz = A.z, d2 = A.w;
            float r0 = B.x, nij = B.y, qq = B.z;
            float Fx = s_F[m*3+0], Fy = s_F[m*3+1], Fz = s_F[m*3+2];
            float d = sqrtf(d2);
            float inv_d = 1.f/d;
            float Bc = fabsf(qq)*__expf((nij - 1.f)*__logf(r0))/nij;
            float er = erfcf(SQRT_ALPHA_C*d);
            float expt = __expf(-ALPHA_C*d2);
            float dmn = __expf(-nij*__logf(d));
            float fp = -ACONST_C*expt*inv_d - er*inv_d*inv_d;
            float Up = 0.5f*KE_C*(qq*fp - Bc*nij*dmn*inv_d);
            float fpp = ACONST_C*expt*(2.f*ALPHA_C + 2.f*inv_d*inv_d) + 2.f*er*inv_d*inv_d*inv_d;
            float Upp = 0.5f*KE_C*(qq*fpp + Bc*nij*(nij+1.f)*dmn*inv_d*inv_d);
            float ui = Up*inv_d;
            float ddot = (rx*Fx + ry*Fy + rz*Fz)*inv_d;
            float c1 = (Upp - ui)*ddot*inv_d;
            // sign (fj-fi) cancels: contrib = c1*r + ui*F
            atomicAdd(&s_hv[m*3+0], c1*rx + ui*Fx);
            atomicAdd(&s_hv[m*3+1], c1*ry + ui*Fy);
            atomicAdd(&s_hv[m*3+2], c1*rz + ui*Fz);
        }
        __syncthreads();
        if (tid < NMOL*3){
            float v = s_hv[tid];
            if (v != 0.f) unsafeAtomicAdd(&g_SH[tid/3][tid%3], v);
        }
    } else {
        int rb = blockIdx.x - PB1;
        int n = rb*256 + tid;
        int m = n >> LOG2PERM;
        float2* s_u = (float2*)s_mem;
        float2* s_v = (float2*)(s_mem + 2*NKKH);
        if (tid < 6) s_b[tid] = g_recipM[m][tid];
        float Fx = -g_SG[m][0], Fy = -g_SG[m][1], Fz = -g_SG[m][2];
        float DD = 0.f;
        for (int mm = 0; mm < NMOL; ++mm) DD += -g_SG[mm][2]*g_qfilm[mm];
        for (int h = tid; h < NKKH; h += 256){
            float4 kv = g_kvch[m*NKKH + h];
            float2 S = g_S[m*NKKH + h];
            s_u[h] = make_float2(kv.w*S.x, kv.w*S.y);
            float2 Sf = g_Sf[m*NKKH + h];
            float kvF = kv.x*Fx + kv.y*Fy + kv.z*Fz;
            s_v[h] = make_float2(-kv.w*kvF*Sf.y, kv.w*kvF*Sf.x);
        }
        __syncthreads();
        float4 th4 = g_TH[n];
        float th1 = th4.x, th2 = th4.y, qn = th4.z;
        float film = (float)g_filmb[n];
        float b1x=s_b[0], b1y=s_b[1], b1z=s_b[2];
        float b2x=s_b[3], b2y=s_b[4], b2z=s_b[5];
        float E1s, E1c, E2s, E2c, Q0s, Q0c;
        sincosf(th1, &E1s, &E1c);
        sincosf(th2, &E2s, &E2c);
        sincosf(-12.f*th2, &Q0s, &Q0c);
        float phi1 = film*(b1x*Fx + b1y*Fy + b1z*Fz);
        float phi2 = film*(b2x*Fx + b2y*Fy + b2z*Fz);
        float A1 = 0.f, A2 = 0.f;
        int h = 0;
        {
            float pc = E2c, ps = E2s;
            for (int kyi = 1; kyi <= 12; ++kyi, ++h){
                float2 u = s_u[h];
                float2 v = s_v[h];
                float thd = (float)kyi*phi2;
                float t = v.y*pc - v.x*ps - (u.y*ps + u.x*pc)*thd;
                A2 += t*(float)kyi;
                float npc = pc*E2c - ps*E2s;
                float nps = pc*E2s + ps*E2c;
                pc = npc; ps = nps;
            }
        }
        float Pc = E1c, Ps = E1s;
        for (int kxi = 1; kxi <= 12; ++kxi){
            float fkx = (float)kxi;
            float pc = Pc*Q0c - Ps*Q0s;
            float ps = Pc*Q0s + Ps*Q0c;
            for (int kyi = 0; kyi < 25; ++kyi, ++h){
                float fky = (float)(kyi - 12);
                float2 u = s_u[h];
                float2 v = s_v[h];
                float thd = fkx*phi1 + fky*phi2;
                float t = v.y*pc - v.x*ps - (u.y*ps + u.x*pc)*thd;
                A1 += t*fkx; A2 += t*fky;
                float npc = pc*E2c - ps*E2s;
                float nps = pc*E2s + ps*E2c;
                pc = npc; ps = nps;
            }
            float nPc = Pc*E1c - Ps*E1s;
            float nPs = Pc*E1s + Ps*E1c;
            Pc = nPc; Ps = nPs;
        }
        A1 *= 2.f; A2 *= 2.f;
        float sc = 2.f*KE_C*qn;
        float slab = 2.f*KE_C*g_C2*qn*DD;
        float sx = film*(sc*(A1*b1x + A2*b2x));
        float sy = film*(sc*(A1*b1y + A2*b2y));
        float sz = film*(sc*(A1*b1z + A2*b2z) + slab);
        sx = waveReduce(sx); sy = waveReduce(sy); sz = waveReduce(sz);
        int lane = tid & 63, wv = tid >> 6;
        if (!lane){ sred[wv] = sx; sred[4+wv] = sy; sred[8+wv] = sz; }
        __syncthreads();
        if (tid == 0){
            unsafeAtomicAdd(&g_SH[m][0], sred[0]+sred[1]+sred[2]+sred[3]);
            unsafeAtomicAdd(&g_SH[m][1], sred[4]+sred[5]+sred[6]+sred[7]);
            unsafeAtomicAdd(&g_SH[m][2], sred[8]+sred[9]+sred[10]+sred[11]);
        }
    }
}

// outputs + re-zero accumulators (zero-at-end protocol)
__global__ __launch_bounds__(512) void k_final(float* out){
    int tid = threadIdx.x;
    int m = tid >> 6, lane = tid & 63;
    float acc = 0.f;
    for (int h = lane; h < NKKH; h += 64){
        float4 kv = g_kvch[m*NKKH + h];
        float2 S = g_S[m*NKKH + h];
        acc += kv.w*(S.x*S.x + S.y*S.y);
    }
    acc = waveReduce(acc);
    if (lane == 0){
        float yew = 2.f*acc;
        float D = g_D;
        float yslab = KE_C*(TWO_PI_C/g_vbox[m])*D*D;
        float yrecip = KE_C*(yew - SELF_C*g_self[m]) + yslab;
        float yr = 0.5f*KE_C*g_yreal[m];
        float yb = 0.5f*KE_C*g_yborn[m];
        float yc = yr + yrecip;
        float fx = -g_SG[m][0], fy = -g_SG[m][1], fz = -g_SG[m][2];
        out[0  + m] = yc + yb;
        out[8  + m] = yc;
        out[16 + m] = yb;
        out[24 + m] = fx*fx + fy*fy + fz*fz;
        out[32 + 3*m + 0] = -2.f*g_SH[m][0];
        out[32 + 3*m + 1] = -2.f*g_SH[m][1];
        out[32 + 3*m + 2] = -2.f*g_SH[m][2];
    }
    __syncthreads();
    if (tid < NMOL){
        g_self[tid] = 0.f; g_qfilm[tid] = 0.f;
        g_yreal[tid] = 0.f; g_yborn[tid] = 0.f;
#pragma unroll
        for (int c = 0; c < 3; ++c){ g_SG[tid][c] = 0.f; g_SH[tid][c] = 0.f; }
    }
    if (tid == 0){ g_D = 0.f; g_nrec = 0; }
}

extern "C" void kernel_launch(void* const* d_in, const int* in_sizes, int n_in,
                              void* d_out, int out_size, void* d_ws, size_t ws_size,
                              hipStream_t stream){
    const float* q       = (const float*)d_in[0];
    const float* R       = (const float*)d_in[1];
    const float* shift   = (const float*)d_in[2];
    const float* cell    = (const float*)d_in[3];
    const float* offsets = (const float*)d_in[4];
    const float* r0_ij   = (const float*)d_in[5];
    const float* n_ij    = (const float*)d_in[6];
    const int*   idx_i   = (const int*)d_in[7];
    const int*   idx_j   = (const int*)d_in[8];
    const int*   is_film = (const int*)d_in[10];
    float* out = (float*)d_out;

    k_init<<<dim3(1 + NATOM/256), dim3(256), 0, stream>>>(cell, q, R, shift, is_film);
    k_fsf<<<dim3(NFILT + NSFB), dim3(256), 0, stream>>>(idx_i, idx_j, offsets, r0_ij, n_ij);
    k_rg0<<<dim3(NATOM/128), dim3(128), 0, stream>>>();
    k_pass1<<<dim3(PB1 + RB1), dim3(256), 0, stream>>>();
    k_final<<<dim3(1), dim3(512), 0, stream>>>(out);
}

// Round 9
// 80.310 us; speedup vs baseline: 5.9579x; 1.3899x over previous
//
#include <hip/hip_runtime.h>
#include <math.h>

#define NATOM 32768
#define NMOL 8
#define PERM 4096
#define LOG2PERM 12
#define NPAIR 2097152
#define NKKH 312          // half k-grid: kx=0,ky=1..12 (12) + kx=1..12,ky=-12..12 (300)
#define CAPREC 393216     // compacted fi!=fj survivor records (~105k expected)
#define NFILT 2048        // filter blocks (1024 pairs each)
#define NSFB (NMOL*50)    // sfac blocks
#define PB1 256           // pass1 pair blocks

#define KE_C 14.3996f
#define ALPHA_C 0.3f
#define SQRT_ALPHA_C 0.5477225575051661f   // sqrt(0.3)
#define ACONST_C 0.6180387232371366f       // 2*sqrt(alpha/pi)
#define SELF_C 0.3090193616185683f         // sqrt(alpha/pi)
#define TWO_PI_C 6.283185307179586f
#define LN_CUTOFF_C 1.791759469228055f     // ln(6)

// persistent device state; accumulators follow zero-at-end protocol
// (.bss zero at load; k_final re-zeroes after use). g_Fm/g_SHr/g_Dd are
// overwritten (not accumulated) each launch.
__device__ float4 g_X[NATOM];            // x,y,z, q with film bit packed in mantissa LSB
__device__ float4 g_TH[NATOM];           // th1,th2,q,q*film
__device__ float4 g_kvch[NMOL*NKKH];     // kvx,kvy,kvz,coef
__device__ float2 g_S[NMOL*NKKH];        // structure factor (all atoms)
__device__ float2 g_Sf[NMOL*NKKH];       // structure factor (q*film)
__device__ float4 g_recA[CAPREC];        // rx, ry, rz, d2
__device__ float4 g_recB[CAPREC];        // r0, n, qq, m
__device__ int   g_nrec;
__device__ float g_recipM[NMOL][9];
__device__ float g_vbox[NMOL];
__device__ float g_self[NMOL], g_qfilm[NMOL];
__device__ float g_yreal[NMOL], g_yborn[NMOL];
__device__ float g_SG[NMOL][3];          // sum film*G, pair part (accumulated)
__device__ float g_SH[NMOL][3];          // sum film*HV, pair part (accumulated)
__device__ float g_Fm[NMOL][3];          // F per molecule (overwritten by k_mid)
__device__ float g_SHr[NMOL][3];         // recip part of sum film*HV (overwritten)
__device__ float g_D, g_C2, g_FRC;

__device__ __forceinline__ float waveReduce(float v){
#pragma unroll
    for (int off = 32; off > 0; off >>= 1) v += __shfl_down(v, off, 64);
    return v;
}

__device__ __forceinline__ void invCell(const float* c, float rm[9], float& vb){
    float a=c[0],b=c[1],cc=c[2],d=c[3],e=c[4],f=c[5],g=c[6],h=c[7],i=c[8];
    float det = a*(e*i - f*h) - b*(d*i - f*g) + cc*(d*h - e*g);
    float inv = 1.f/det;
    rm[0]=TWO_PI_C*(e*i-f*h)*inv;  rm[1]=TWO_PI_C*(f*g-d*i)*inv;  rm[2]=TWO_PI_C*(d*h-e*g)*inv;
    rm[3]=TWO_PI_C*(cc*h-b*i)*inv; rm[4]=TWO_PI_C*(a*i-cc*g)*inv; rm[5]=TWO_PI_C*(b*g-a*h)*inv;
    rm[6]=TWO_PI_C*(b*f-cc*e)*inv; rm[7]=TWO_PI_C*(cc*d-a*f)*inv; rm[8]=TWO_PI_C*(a*e-b*d)*inv;
    vb = fabsf(det);
}

// block 0: k-vector table + constants; blocks 1..128: shift + TH + scalar sums
__global__ __launch_bounds__(256) void k_init(const float* cell, const float* q,
                                              const float* R, const float* shift,
                                              const int* is_film){
    __shared__ float s_rm[NMOL][9];
    __shared__ float s_vb[NMOL];
    __shared__ float red[12];
    int tid = threadIdx.x;
    if (tid < NMOL){
        float rm[9], vb;
        invCell(cell + 9*tid, rm, vb);
#pragma unroll
        for (int k = 0; k < 9; ++k) s_rm[tid][k] = rm[k];
        s_vb[tid] = vb;
    }
    __syncthreads();
    if (blockIdx.x == 0){
        if (tid < NMOL){
#pragma unroll
            for (int k = 0; k < 9; ++k) g_recipM[tid][k] = s_rm[tid][k];
            g_vbox[tid] = s_vb[tid];
        }
        if (tid == 0){
            float c2 = 0.f;
            for (int mm = 0; mm < NMOL; ++mm) c2 += TWO_PI_C/s_vb[mm];
            g_C2 = c2;
            g_FRC = (float)(erfc(sqrt(0.3)*6.0)/6.0);
        }
        for (int id = tid; id < NMOL*NKKH; id += 256){
            int m = id / NKKH, h = id % NKKH;
            int kx, ky;
            if (h < 12){ kx = 0; ky = h + 1; }
            else { int t = h - 12; kx = t/25 + 1; ky = t%25 - 12; }
            float fkx = (float)kx, fky = (float)ky;
            float nrm = fkx*fkx + fky*fky;
            float kvx = fkx*s_rm[m][0] + fky*s_rm[m][3];
            float kvy = fkx*s_rm[m][1] + fky*s_rm[m][4];
            float kvz = fkx*s_rm[m][2] + fky*s_rm[m][5];
            float coef = 0.f;
            if (nrm <= 146.f){
                float ksq = kvx*kvx + kvy*kvy + kvz*kvz;
                coef = (TWO_PI_C/s_vb[m]) * expf(-0.25f*ksq/ALPHA_C) / ksq;
            }
            g_kvch[id] = make_float4(kvx, kvy, kvz, coef);
        }
    } else {
        int n = (blockIdx.x - 1)*256 + tid;
        int m = n >> LOG2PERM;
        int film = is_film[n];
        float qn = q[n];
        float x = R[3*n+0], y = R[3*n+1], z = R[3*n+2];
        if (film){ x += shift[3*m+0]; y += shift[3*m+1]; z += shift[3*m+2]; }
        // pack film into q's mantissa LSB (<=1 ulp perturbation of q)
        unsigned qb = (__float_as_uint(qn) & ~1u) | (unsigned)film;
        g_X[n] = make_float4(x, y, z, __uint_as_float(qb));
        float qf = film ? qn : 0.f;
        float th1 = s_rm[m][0]*x + s_rm[m][1]*y + s_rm[m][2]*z;
        float th2 = s_rm[m][3]*x + s_rm[m][4]*y + s_rm[m][5]*z;
        g_TH[n] = make_float4(th1, th2, qn, qf);
        float vD = waveReduce(qn*z);
        float vS = waveReduce(qn*qn);
        float vQ = waveReduce(qf);
        int lane = tid & 63, w = tid >> 6;
        if (!lane){ red[w] = vD; red[4+w] = vS; red[8+w] = vQ; }
        __syncthreads();
        if (tid == 0){
            unsafeAtomicAdd(&g_D, red[0]+red[1]+red[2]+red[3]);
            unsafeAtomicAdd(&g_self[m], red[4]+red[5]+red[6]+red[7]);
            unsafeAtomicAdd(&g_qfilm[m], red[8]+red[9]+red[10]+red[11]);
        }
    }
}

// blocks [0,NFILT): filter + fused pass-0 pair sweep
// blocks [NFILT,NFILT+NSFB): structure factors via phasor recurrence
__global__ __launch_bounds__(256) void k_fsf(const int* idx_i, const int* idx_j,
                                             const float* offsets,
                                             const float* r0_ij, const float* n_ij){
    __shared__ float s_red[160];
    __shared__ float s_acc[NMOL*5];   // fx,fy,fz,ereal,eborn per molecule
    __shared__ int s_cnt, s_base;
    int tid = threadIdx.x;
    if (blockIdx.x < NFILT){
        if (tid < NMOL*5) s_acc[tid] = 0.f;
        if (tid == 0) s_cnt = 0;
        int p0 = blockIdx.x*1024 + tid*4;     // 4 consecutive pairs
        int4 ii = *(const int4*)(idx_i + p0);
        int4 jj = *(const int4*)(idx_j + p0);
        float4 r04 = *(const float4*)(r0_ij + p0);
        float4 n4  = *(const float4*)(n_ij + p0);
        const float4* ob = (const float4*)(offsets + 3*p0);
        float4 o0 = ob[0], o1 = ob[1], o2 = ob[2];
        int ia[4] = {ii.x, ii.y, ii.z, ii.w};
        int ja[4] = {jj.x, jj.y, jj.z, jj.w};
        float oxa[4] = {o0.x, o0.w, o1.z, o2.y};
        float oya[4] = {o0.y, o1.x, o1.w, o2.z};
        float oza[4] = {o0.z, o1.y, o2.x, o2.w};
        float r0a[4] = {r04.x, r04.y, r04.z, r04.w};
        float na[4]  = {n4.x, n4.y, n4.z, n4.w};
        float4 xi[4], xj[4];
#pragma unroll
        for (int k = 0; k < 4; ++k){ xi[k] = g_X[ia[k]]; xj[k] = g_X[ja[k]]; }
        float FRC = g_FRC;
        __syncthreads();
        float rsx[4], rsy[4], rsz[4], sd2[4], sr0[4], snn[4], sqq[4];
        int smm[4], rk[4];
        bool st[4];
#pragma unroll
        for (int k = 0; k < 4; ++k){
            st[k] = false;
            float rx = xj[k].x - xi[k].x + oxa[k];
            float ry = xj[k].y - xi[k].y + oya[k];
            float rz = xj[k].z - xi[k].z + oza[k];
            float d2v = rx*rx + ry*ry + rz*rz;
            if (d2v < 36.f){
                unsigned fi = __float_as_uint(xi[k].w) & 1u;
                unsigned fj = __float_as_uint(xj[k].w) & 1u;
                float d = sqrtf(d2v);
                float inv_d = 1.f/d;
                float qq = xi[k].w*xj[k].w;
                float nij = na[k], r0 = r0a[k];
                float Bc = fabsf(qq)*__expf((nij - 1.f)*__logf(r0))/nij;
                float er = erfcf(SQRT_ALPHA_C*d);
                float expt = __expf(-ALPHA_C*d2v);
                float dmn = __expf(-nij*__logf(d));
                float fp = -ACONST_C*expt*inv_d - er*inv_d*inv_d;
                float Up = 0.5f*KE_C*(qq*fp - Bc*nij*dmn*inv_d);
                int m = ia[k] >> LOG2PERM;
                atomicAdd(&s_acc[m*5+3], qq*(er*inv_d - FRC));
                atomicAdd(&s_acc[m*5+4], Bc*(dmn - __expf(-nij*LN_CUTOFF_C)));
                if (fi != fj){
                    float fdiff = (float)fj - (float)fi;
                    float sc = Up*inv_d;
                    atomicAdd(&s_acc[m*5+0], fdiff*sc*rx);
                    atomicAdd(&s_acc[m*5+1], fdiff*sc*ry);
                    atomicAdd(&s_acc[m*5+2], fdiff*sc*rz);
                    rk[k] = atomicAdd(&s_cnt, 1);
                    st[k] = true;
                    rsx[k]=rx; rsy[k]=ry; rsz[k]=rz; sd2[k]=d2v;
                    sr0[k]=r0; snn[k]=nij; sqq[k]=qq; smm[k]=m;
                }
            }
        }
        __syncthreads();
        if (tid == 0) s_base = atomicAdd(&g_nrec, s_cnt);
        __syncthreads();
#pragma unroll
        for (int k = 0; k < 4; ++k) if (st[k]){
            int slot = s_base + rk[k];
            if (slot < CAPREC){
                g_recA[slot] = make_float4(rsx[k], rsy[k], rsz[k], sd2[k]);
                g_recB[slot] = make_float4(sr0[k], snn[k], sqq[k], (float)smm[k]);
            }
        }
        if (tid < NMOL*5){
            float v = s_acc[tid];
            if (v != 0.f){
                int m = tid/5, c = tid%5;
                if (c < 3) unsafeAtomicAdd(&g_SG[m][c], v);
                else if (c == 3) unsafeAtomicAdd(&g_yreal[m], v);
                else unsafeAtomicAdd(&g_yborn[m], v);
            }
        }
    } else {
        int sb = blockIdx.x - NFILT;
        int m = sb / 50, c = sb % 50;
        int kx, ky0, h0, len;
        if (c < 2){ kx = 0; ky0 = 1 + 8*c; h0 = 8*c; len = c ? 4 : 8; }
        else { int t = c - 2; kx = t/4 + 1; int s4 = t%4; ky0 = -12 + 8*s4; h0 = 12 + (kx-1)*25 + 8*s4; len = (s4==3) ? 1 : 8; }
        float fkx = (float)kx, fky0 = (float)ky0;
        int base = m << LOG2PERM;
        float aR[8], aI[8], bR[8], bI[8];
#pragma unroll
        for (int e = 0; e < 8; ++e){ aR[e]=0.f; aI[e]=0.f; bR[e]=0.f; bI[e]=0.f; }
        for (int a = 0; a < 16; ++a){
            float4 th = g_TH[base + tid + a*256];
            float s, cc, s2, c2;
            __sincosf(fkx*th.x + fky0*th.y, &s, &cc);
            __sincosf(th.y, &s2, &c2);
            float qv = th.z, qf = th.w;
#pragma unroll
            for (int e = 0; e < 8; ++e){
                aR[e] += qv*cc; aI[e] += qv*s;
                bR[e] += qf*cc; bI[e] += qf*s;
                float nc = cc*c2 - s*s2;
                float ns = cc*s2 + s*c2;
                cc = nc; s = ns;
            }
        }
        int lane = tid & 63, wid = tid >> 6;
#pragma unroll
        for (int e = 0; e < 8; ++e){
            float v0 = waveReduce(aR[e]), v1 = waveReduce(aI[e]);
            float v2 = waveReduce(bR[e]), v3 = waveReduce(bI[e]);
            if (!lane){
                s_red[(e*4+0)*4+wid] = v0; s_red[(e*4+1)*4+wid] = v1;
                s_red[(e*4+2)*4+wid] = v2; s_red[(e*4+3)*4+wid] = v3;
            }
        }
        __syncthreads();
        if (tid < 32){
            float v = s_red[tid*4+0]+s_red[tid*4+1]+s_red[tid*4+2]+s_red[tid*4+3];
            int e = tid >> 2, comp = tid & 3;
            if (e < len){
                int idx = m*NKKH + h0 + e;
                if (comp == 0) g_S[idx].x = v;
                else if (comp == 1) g_S[idx].y = v;
                else if (comp == 2) g_Sf[idx].x = v;
                else g_Sf[idx].y = v;
            }
        }
    }
}

// one block, wave w = molecule w. Contracts the reciprocal gradient sums over
// atoms analytically via S/Sf, computes F_m, Dd, SHr, and the energy outputs.
__global__ __launch_bounds__(512) void k_mid(float* out){
    __shared__ float s_F[NMOL][3];
    __shared__ float s_Dd;
    int tid = threadIdx.x;
    int m = tid >> 6, lane = tid & 63;
    // phase A: sum film*G_recip = 2KE*2*sum_k c*(S_im Sf_re - S_re Sf_im)*kvec
    float gx = 0.f, gy = 0.f, gz = 0.f, yew = 0.f;
    for (int h = lane; h < NKKH; h += 64){
        float4 kv = g_kvch[m*NKKH + h];
        float2 S = g_S[m*NKKH + h];
        float2 Sf = g_Sf[m*NKKH + h];
        float w = kv.w*(S.y*Sf.x - S.x*Sf.y);
        gx += w*kv.x; gy += w*kv.y; gz += w*kv.z;
        yew += kv.w*(S.x*S.x + S.y*S.y);
    }
    gx = waveReduce(gx); gy = waveReduce(gy); gz = waveReduce(gz); yew = waveReduce(yew);
    if (lane == 0){
        float D = g_D, qfm = g_qfilm[m];
        float sgrx = 4.f*KE_C*gx;
        float sgry = 4.f*KE_C*gy;
        float sgrz = 4.f*KE_C*gz + 2.f*KE_C*g_C2*D*qfm;
        float fx = -(g_SG[m][0] + sgrx);
        float fy = -(g_SG[m][1] + sgry);
        float fz = -(g_SG[m][2] + sgrz);
        s_F[m][0] = fx; s_F[m][1] = fy; s_F[m][2] = fz;
        g_Fm[m][0] = fx; g_Fm[m][1] = fy; g_Fm[m][2] = fz;
        float yslab = KE_C*(TWO_PI_C/g_vbox[m])*D*D;
        float yrecip = KE_C*(2.f*yew - SELF_C*g_self[m]) + yslab;
        float yr = 0.5f*KE_C*g_yreal[m];
        float yb = 0.5f*KE_C*g_yborn[m];
        float yc = yr + yrecip;
        out[0  + m] = yc + yb;
        out[8  + m] = yc;
        out[16 + m] = yb;
        out[24 + m] = fx*fx + fy*fy + fz*fz;
    }
    __syncthreads();
    if (tid == 0){
        float dd = 0.f;
        for (int mm = 0; mm < NMOL; ++mm) dd += s_F[mm][2]*g_qfilm[mm];
        s_Dd = dd;
    }
    __syncthreads();
    // phase B: sum film*HV_recip = 2KE*2*sum_k c*(k.F)*(|Sf|^2 - Re(S conj Sf))*kvec
    float Fx = s_F[m][0], Fy = s_F[m][1], Fz = s_F[m][2];
    float hx = 0.f, hy = 0.f, hz = 0.f;
    for (int h = lane; h < NKKH; h += 64){
        float4 kv = g_kvch[m*NKKH + h];
        float2 S = g_S[m*NKKH + h];
        float2 Sf = g_Sf[m*NKKH + h];
        float kF = kv.x*Fx + kv.y*Fy + kv.z*Fz;
        float w = kv.w*kF*((Sf.x*Sf.x + Sf.y*Sf.y) - (S.x*Sf.x + S.y*Sf.y));
        hx += w*kv.x; hy += w*kv.y; hz += w*kv.z;
    }
    hx = waveReduce(hx); hy = waveReduce(hy); hz = waveReduce(hz);
    if (lane == 0){
        g_SHr[m][0] = 4.f*KE_C*hx;
        g_SHr[m][1] = 4.f*KE_C*hy;
        g_SHr[m][2] = 4.f*KE_C*hz + 2.f*KE_C*g_C2*s_Dd*g_qfilm[m];
    }
}

// HVP pair sweep over compacted records (register compute, tiny LDS sums)
__global__ __launch_bounds__(256) void k_pass1(){
    __shared__ float s_F[NMOL*3];
    __shared__ float s_hv[NMOL*3];
    int tid = threadIdx.x;
    if (tid < NMOL*3){
        s_F[tid] = g_Fm[tid/3][tid%3];
        s_hv[tid] = 0.f;
    }
    __syncthreads();
    int nrec = g_nrec; if (nrec > CAPREC) nrec = CAPREC;
    for (int r = blockIdx.x*256 + tid; r < nrec; r += PB1*256){
        float4 A = g_recA[r];
        float4 B = g_recB[r];
        int m = (int)B.w;
        float rx = A.x, ry = A.y, rz = A.z, d2 = A.w;
        float r0 = B.x, nij = B.y, qq = B.z;
        float Fx = s_F[m*3+0], Fy = s_F[m*3+1], Fz = s_F[m*3+2];
        float d = sqrtf(d2);
        float inv_d = 1.f/d;
        float Bc = fabsf(qq)*__expf((nij - 1.f)*__logf(r0))/nij;
        float er = erfcf(SQRT_ALPHA_C*d);
        float expt = __expf(-ALPHA_C*d2);
        float dmn = __expf(-nij*__logf(d));
        float fp = -ACONST_C*expt*inv_d - er*inv_d*inv_d;
        float Up = 0.5f*KE_C*(qq*fp - Bc*nij*dmn*inv_d);
        float fpp = ACONST_C*expt*(2.f*ALPHA_C + 2.f*inv_d*inv_d) + 2.f*er*inv_d*inv_d*inv_d;
        float Upp = 0.5f*KE_C*(qq*fpp + Bc*nij*(nij+1.f)*dmn*inv_d*inv_d);
        float ui = Up*inv_d;
        float ddot = (rx*Fx + ry*Fy + rz*Fz)*inv_d;
        float c1 = (Upp - ui)*ddot*inv_d;
        // sign (fj-fi) cancels: contrib = c1*r + ui*F
        atomicAdd(&s_hv[m*3+0], c1*rx + ui*Fx);
        atomicAdd(&s_hv[m*3+1], c1*ry + ui*Fy);
        atomicAdd(&s_hv[m*3+2], c1*rz + ui*Fz);
    }
    __syncthreads();
    if (tid < NMOL*3){
        float v = s_hv[tid];
        if (v != 0.f) unsafeAtomicAdd(&g_SH[tid/3][tid%3], v);
    }
}

// gradient outputs + re-zero accumulators (zero-at-end protocol)
__global__ __launch_bounds__(64) void k_final(float* out){
    int tid = threadIdx.x;
    if (tid < NMOL*3){
        int m = tid/3, c = tid%3;
        out[32 + tid] = -2.f*(g_SH[m][c] + g_SHr[m][c]);
    }
    __syncthreads();
    if (tid < NMOL){
        g_self[tid] = 0.f; g_qfilm[tid] = 0.f;
        g_yreal[tid] = 0.f; g_yborn[tid] = 0.f;
#pragma unroll
        for (int c = 0; c < 3; ++c){ g_SG[tid][c] = 0.f; g_SH[tid][c] = 0.f; }
    }
    if (tid == 0){ g_D = 0.f; g_nrec = 0; }
}

extern "C" void kernel_launch(void* const* d_in, const int* in_sizes, int n_in,
                              void* d_out, int out_size, void* d_ws, size_t ws_size,
                              hipStream_t stream){
    const float* q       = (const float*)d_in[0];
    const float* R       = (const float*)d_in[1];
    const float* shift   = (const float*)d_in[2];
    const float* cell    = (const float*)d_in[3];
    const float* offsets = (const float*)d_in[4];
    const float* r0_ij   = (const float*)d_in[5];
    const float* n_ij    = (const float*)d_in[6];
    const int*   idx_i   = (const int*)d_in[7];
    const int*   idx_j   = (const int*)d_in[8];
    const int*   is_film = (const int*)d_in[10];
    float* out = (float*)d_out;

    k_init<<<dim3(1 + NATOM/256), dim3(256), 0, stream>>>(cell, q, R, shift, is_film);
    k_fsf<<<dim3(NFILT + NSFB), dim3(256), 0, stream>>>(idx_i, idx_j, offsets, r0_ij, n_ij);
    k_mid<<<dim3(1), dim3(512), 0, stream>>>(out);
    k_pass1<<<dim3(PB1), dim3(256), 0, stream>>>();
    k_final<<<dim3(1), dim3(64), 0, stream>>>(out);
}